// Round 12
// baseline (66043.463 us; speedup 1.0000x reference)
//
#include <hip/hip_runtime.h>
#include <math.h>

// ---------------------------------------------------------------------------
// LSTM_FEAT_2: T=4096 sequential 2-layer LSTM + log-softmax feedback.
// R12: gap count 3 -> 2 via BASE-GATE records (lse factored out of the
// critical exchange).
//  - gates1 = base - rsWC[row]*lse is AFFINE in lse -> producer publishes
//    {i,f,g,seq}+{o,c_prev,seq} base records WITHOUT waiting for lse;
//  - every consumer thread applies -d*lse + sigm/tanh locally for its 2
//    h1 elements (identical fp32 op order in all wgs -> deterministic);
//  - ry (for lse) is published a full dot-phase before consumption ->
//    its RT hides under compute + the rg1 gap; serial chain per step is
//    now rh2-gap -> compute -> rg1-gap -> B-dot (2 exposed gaps, was 3);
//  - per-thread rsWC rows from colsum(Wm) trick at init (8 pinned floats);
//  - c1 state is record-carried; owner threads stash c_new to s_c1 for
//    next step's record.
//
// Math (unchanged, verified R7-R11):
//   feat_t = Ws@x_t + bs                       (startup kernel)
//   gates1 = [Wih1s|Whh1]@[feat;h1] + WCL@h2 + biasA [+ biasE2 - rsWC*lse]
//     WCL=(Wih1e@Wm)@Wl, biasE2=Wih1e@bm+WC@bl, rsWC=rowsum(WC)
//   gates2 = [Wih2|Whh2]@[h1;h2] + biasB
//   y_t    = Wl@h2_t + bl -> d_out ; post-pass: out = log_softmax(out)
// ---------------------------------------------------------------------------

#define T_STEPS 4096
#define NWG 256

typedef unsigned u32x4 __attribute__((ext_vector_type(4)));

// ws layout (bytes)
#define WS_RG1   0            // u32x4[2][2048]: base-gate recs, 2 per h1 elem (64KB)
#define WS_RH2   65536        // u32x4[2][512]: h2 records {h,h,seq,0} (16KB)
#define WS_RY    81920        // u32x4[2][256]: y records {y0,y1,seq,0} (8KB)
#define WS_ZERO_BYTES 90112
#define WS_FEAT  90112        // float[4096][512] -> end ~8.5MB

// dynamic LDS partition (floats)
#define OFF_WA 2560           // s_in[2560] | wa[16][1024] | wb[16][768] | wy[2][1024]
#define OFF_WB 18944
#define OFF_WY 31232
#define SMEM_FLOATS 33280
#define SMEM_BYTES  (SMEM_FLOATS*4)

#define PIN4(v) asm volatile("" : "+v"((v).x), "+v"((v).y), "+v"((v).z), "+v"((v).w))
#define PIN1(v) asm volatile("" : "+v"(v))
#define FMA4(acc,s,v4) {(acc).x += (s)*(v4).x; (acc).y += (s)*(v4).y; (acc).z += (s)*(v4).z; (acc).w += (s)*(v4).w;}
#define DOT4(a,b) ((a).x*(b).x + (a).y*(b).y + (a).z*(b).z + (a).w*(b).w)

// coherent 16B transactional load/store (bypass L1/L2 -> LLC)
__device__ __forceinline__ u32x4 ld16(const u32x4* p){
  u32x4 r;
  asm volatile("global_load_dwordx4 %0, %1, off sc0 sc1\n\ts_waitcnt vmcnt(0)"
               : "=v"(r) : "v"(p) : "memory");
  return r;
}
// 4 contiguous records, ONE waitcnt (offset immediates)
__device__ __forceinline__ void ld16x4(const u32x4* p, u32x4& r0, u32x4& r1,
                                       u32x4& r2, u32x4& r3){
  asm volatile("global_load_dwordx4 %0, %4, off sc0 sc1\n\t"
               "global_load_dwordx4 %1, %4, off offset:16 sc0 sc1\n\t"
               "global_load_dwordx4 %2, %4, off offset:32 sc0 sc1\n\t"
               "global_load_dwordx4 %3, %4, off offset:48 sc0 sc1\n\t"
               "s_waitcnt vmcnt(0)"
               : "=&v"(r0), "=&v"(r1), "=&v"(r2), "=&v"(r3)
               : "v"(p) : "memory");
}
__device__ __forceinline__ void st16(u32x4* p, u32x4 v){
  asm volatile("global_store_dwordx4 %0, %1, off sc0 sc1"
               :: "v"(p), "v"(v) : "memory");
}
__device__ __forceinline__ float sigm(float x){ return 1.0f/(1.0f+expf(-x)); }

// ---------------------------------------------------------------------------
// startup: feat[t][k] = Ws[k]·x[t] + bs[k]
__global__ __launch_bounds__(512) void feat_kernel(
    const float* __restrict__ x, const float* __restrict__ Ws,
    const float* __restrict__ bs, float* __restrict__ feat)
{
  __shared__ float s_x[16][360];
  __shared__ float s_w[512][20];
  const int bid = blockIdx.x, tid = threadIdx.x;
  const int t0 = bid * 16;
  for (int tt = 0; tt < 16; tt++)
    if (tid < 360) s_x[tt][tid] = x[(t0+tt)*360 + tid];
  float acc[16];
  #pragma unroll
  for (int i = 0; i < 16; i++) acc[i] = 0.f;
  for (int d0 = 0; d0 < 360; d0 += 16){
    const int dn = (360 - d0 < 16) ? (360 - d0) : 16;
    __syncthreads();
    if (dn == 16){
      #pragma unroll
      for (int c4 = 0; c4 < 4; c4++)
        *(float4*)&s_w[tid][c4*4] = *(const float4*)&Ws[tid*360 + d0 + c4*4];
    } else {
      for (int c = 0; c < dn; c++) s_w[tid][c] = Ws[tid*360 + d0 + c];
    }
    __syncthreads();
    for (int c = 0; c < dn; c++){
      float wv = s_w[tid][c];
      #pragma unroll
      for (int tt = 0; tt < 16; tt++) acc[tt] += wv * s_x[tt][d0 + c];
    }
  }
  for (int tt = 0; tt < 16; tt++)
    feat[(t0+tt)*512 + tid] = acc[tt] + bs[tid];
}

// ---------------------------------------------------------------------------
// post-pass: out[t] = out[t] - logsumexp(out[t])  (in place)
__global__ __launch_bounds__(64) void ls_kernel(float* __restrict__ out)
{
  const int t = blockIdx.x, l = threadIdx.x;
  float v[8];
  #pragma unroll
  for (int i = 0; i < 8; i++) v[i] = out[t*512 + l*8 + i];
  float m0 = v[0];
  #pragma unroll
  for (int i = 1; i < 8; i++) m0 = fmaxf(m0, v[i]);
  #pragma unroll
  for (int mk = 32; mk; mk >>= 1) m0 = fmaxf(m0, __shfl_xor(m0, mk));
  float s = 0.f;
  #pragma unroll
  for (int i = 0; i < 8; i++) s += expf(v[i] - m0);
  #pragma unroll
  for (int mk = 32; mk; mk >>= 1) s += __shfl_xor(s, mk);
  float lse = m0 + logf(s);
  #pragma unroll
  for (int i = 0; i < 8; i++) out[t*512 + l*8 + i] = v[i] - lse;
}

// ---------------------------------------------------------------------------
// persistent kernel: 256 wgs x 512 thr (8 waves), 1 wg/CU via 133KB LDS.
// Wave w owns gate rows {2w,2w+1}; lane l owns f4 col-chunks (bank-clean).
// s_in layout (persistent): feat[0,512) | h1[512,1536) | h2[1536,2560).
// Consumer thread tid re-derives h1 elements {2tid, 2tid+1} from records.
__global__ __launch_bounds__(512, 1) void lstm_persist(
    const float* __restrict__ Wih1, const float* __restrict__ Whh1,
    const float* __restrict__ Wih2, const float* __restrict__ Whh2,
    const float* __restrict__ Wl,   const float* __restrict__ Wm,
    const float* __restrict__ bih1, const float* __restrict__ bhh1,
    const float* __restrict__ bih2, const float* __restrict__ bhh2,
    const float* __restrict__ blp,  const float* __restrict__ bmp,
    char* __restrict__ wsb, float* __restrict__ out)
{
  extern __shared__ float smem[];
  float* s_in = smem;               // feat | h1 | h2 (persistent regions)
  float* wa   = smem + OFF_WA;      // [16][1024] = WCL rows
  float* wb   = smem + OFF_WB;      // [16][768]  = Whh2 cols 256..1023 (init: WCtmp)
  float* wy   = smem + OFF_WY;      // [2][1024]  = Wl rows wid*2, wid*2+1
  __shared__ float s_part[16];
  __shared__ float s_sums[32];
  __shared__ float s_cs[128];
  __shared__ float s_lse[1];
  __shared__ float s_c1[4];

  u32x4* rg1 = (u32x4*)(wsb + WS_RG1);   // [2][2048]
  u32x4* rh2 = (u32x4*)(wsb + WS_RH2);   // [2][512]
  u32x4* ry  = (u32x4*)(wsb + WS_RY);    // [2][256]
  const float* featp = (const float*)(wsb + WS_FEAT);

  const int wid = blockIdx.x, tid = threadIdx.x;
  const int w = tid >> 6, l = tid & 63;
  const int o0 = 2*w, o1 = 2*w + 1;
  const int rA0 = (o0 >> 2)*1024 + wid*4 + (o0 & 3);
  const int rA1 = (o1 >> 2)*1024 + wid*4 + (o1 & 3);

  // ===== init 1: stage this wg's 16 Wih1e rows (16x128) into s_in =====
  for (int idx = tid; idx < 2048; idx += 512){
    int o = idx >> 7, e = idx & 127;
    int r = (o >> 2)*1024 + wid*4 + (o & 3);
    s_in[idx] = Wih1[r*640 + 512 + e];
  }
  // colsum(Wm): cs[e] = sum_m Wm[e][m]
  if (tid < 128){
    float s = 0.f;
    for (int m = 0; m < 512; m += 4){
      float4 v = *(const float4*)&Wm[tid*512 + m];
      s += v.x + v.y + v.z + v.w;
    }
    s_cs[tid] = s;
  }
  __syncthreads();

  // ===== init 2: WCtmp = Wih1e @ Wm  (16x512) -> wb area =====
  {
    float4 a00 = {0,0,0,0}, a01 = a00, a10 = a00, a11 = a00;
    for (int e = 0; e < 128; e++){
      float w0e = s_in[o0*128 + e], w1e = s_in[o1*128 + e];
      float4 m0 = *(const float4*)&Wm[e*512 + l*4];
      float4 m1 = *(const float4*)&Wm[e*512 + l*4 + 256];
      FMA4(a00, w0e, m0); FMA4(a01, w0e, m1);
      FMA4(a10, w1e, m0); FMA4(a11, w1e, m1);
    }
    *(float4*)&wb[o0*512 + l*4]       = a00;
    *(float4*)&wb[o0*512 + l*4 + 256] = a01;
    *(float4*)&wb[o1*512 + l*4]       = a10;
    *(float4*)&wb[o1*512 + l*4 + 256] = a11;
  }
  __syncthreads();

  // ===== init 3: WCL = WCtmp @ Wl (16x1024) -> wa; WC@bl piggyback =====
  {
    float4 c00={0,0,0,0}, c01=c00, c02=c00, c03=c00;
    float4 c10=c00, c11=c00, c12=c00, c13=c00;
    float wl0=0.f, wl1=0.f;
    for (int m = 0; m < 512; m++){
      float t0 = wb[o0*512 + m], t1 = wb[o1*512 + m];
      float blm = blp[m];
      wl0 += t0*blm; wl1 += t1*blm;
      float4 q0 = *(const float4*)&Wl[m*1024 + l*4];
      float4 q1 = *(const float4*)&Wl[m*1024 + l*4 + 256];
      float4 q2 = *(const float4*)&Wl[m*1024 + l*4 + 512];
      float4 q3 = *(const float4*)&Wl[m*1024 + l*4 + 768];
      FMA4(c00,t0,q0); FMA4(c01,t0,q1); FMA4(c02,t0,q2); FMA4(c03,t0,q3);
      FMA4(c10,t1,q0); FMA4(c11,t1,q1); FMA4(c12,t1,q2); FMA4(c13,t1,q3);
    }
    *(float4*)&wa[o0*1024 + l*4      ] = c00;
    *(float4*)&wa[o0*1024 + l*4 + 256] = c01;
    *(float4*)&wa[o0*1024 + l*4 + 512] = c02;
    *(float4*)&wa[o0*1024 + l*4 + 768] = c03;
    *(float4*)&wa[o1*1024 + l*4      ] = c10;
    *(float4*)&wa[o1*1024 + l*4 + 256] = c11;
    *(float4*)&wa[o1*1024 + l*4 + 512] = c12;
    *(float4*)&wa[o1*1024 + l*4 + 768] = c13;
    if (l == 0){ s_sums[w*2+0] = wl0; s_sums[w*2+1] = wl1; }
  }
  __syncthreads();

  // ===== init 4: producer bias regs (wave0); consumer d-vectors (all) =====
  float biasAreg=0.f, biasBreg=0.f, bE2reg=0.f;
  float bl0=0.f, bl1=0.f, c2=0.f;
  if (w == 0 && l < 16){
    int r = (l >> 2)*1024 + wid*4 + (l & 3);
    biasAreg = bih1[r] + bhh1[r];
    biasBreg = bih2[r] + bhh2[r];
    float acc = s_sums[(l>>1)*2 + (l&1)];     // WC@bl for this row
    for (int e = 0; e < 128; e++) acc += s_in[l*128 + e] * bmp[e];
    bE2reg = acc;
  }
  if (w == 0 && l == 0){ bl0 = blp[wid*2]; bl1 = blp[wid*2 + 1]; }
  if (w == 0 && l < 4) s_c1[l] = 0.f;
  // consumer: dE0/dE1 = rsWC rows {e,1024+e,2048+e,3072+e} for e=2tid,2tid+1
  float4 dE0, dE1;
  {
    float dv[8];
    #pragma unroll
    for (int j = 0; j < 2; j++){
      int e = 2*tid + j;
      #pragma unroll
      for (int k = 0; k < 4; k++){
        int r = k*1024 + e;
        float s = 0.f;
        for (int ee = 0; ee < 128; ee += 4){
          float4 wv = *(const float4*)&Wih1[(size_t)r*640 + 512 + ee];
          float4 cv = *(const float4*)&s_cs[ee];
          s += DOT4(wv, cv);
        }
        dv[j*4 + k] = s;
      }
    }
    dE0 = make_float4(dv[0], dv[1], dv[2], dv[3]);
    dE1 = make_float4(dv[4], dv[5], dv[6], dv[7]);
  }
  __syncthreads();     // init4's s_in reads done before zeroing below

  // ===== init 5: zero h1/h2 regions; LDS weights wb (Whh2) and wy (Wl) ====
  for (int idx = tid; idx < 2048; idx += 512) s_in[512 + idx] = 0.f;
  for (int o = 0; o < 16; o++){
    int r = (o >> 2)*1024 + wid*4 + (o & 3);
    for (int c = tid; c < 768; c += 512)
      wb[o*768 + c] = Whh2[r*1024 + 256 + c];
  }
  for (int idx = tid; idx < 2048; idx += 512){
    int row = idx >> 10, c = idx & 1023;
    wy[idx] = Wl[(wid*2 + row)*1024 + c];
  }

  // ===== init 6: pinned register weights (88 floats/thread) =====
  float4 wA0[6], wA1[6], wB0[5], wB1[5];
  #pragma unroll
  for (int j = 0; j < 6; j++){
    int c = 256*j + l*4;
    wA0[j] = (c < 512) ? *(const float4*)&Wih1[rA0*640 + c]
                       : *(const float4*)&Whh1[rA0*1024 + c - 512];
    wA1[j] = (c < 512) ? *(const float4*)&Wih1[rA1*640 + c]
                       : *(const float4*)&Whh1[rA1*1024 + c - 512];
  }
  #pragma unroll
  for (int j = 0; j < 5; j++){
    int c = 256*j + l*4;
    wB0[j] = (c < 1024) ? *(const float4*)&Wih2[rA0*1024 + c]
                        : *(const float4*)&Whh2[rA0*1024 + c - 1024];
    wB1[j] = (c < 1024) ? *(const float4*)&Wih2[rA1*1024 + c]
                        : *(const float4*)&Whh2[rA1*1024 + c - 1024];
  }
  #pragma unroll
  for (int j = 0; j < 6; j++){ PIN4(wA0[j]); PIN4(wA1[j]); }
  #pragma unroll
  for (int j = 0; j < 5; j++){ PIN4(wB0[j]); PIN4(wB1[j]); }
  PIN4(dE0); PIN4(dE1);
  PIN1(biasAreg); PIN1(biasBreg); PIN1(bE2reg);
  PIN1(bl0); PIN1(bl1);
  __syncthreads();

  // ===== main loop =====
  for (int t = 0; t < T_STEPS; t++){
    const int pprev = (t + 1) & 1;       // parity of step t-1
    const int pcur  = t & 1;             // parity of step t
    const unsigned need = (unsigned)(t + 1);

    // ---- A1: stage feat(t) (h1(t-1) already in s_in[512,1536) from B) ----
    if (tid < 256)
      *(float2*)&s_in[tid*2] = *(const float2*)&featp[(size_t)t*512 + tid*2];
    __syncthreads();

    // ---- A2: partial gates1 (feat+h1 cols, reg weights) -- NO h2 dep ----
    float acc0 = 0.f, acc1 = 0.f;
    #pragma unroll
    for (int j = 0; j < 6; j++){
      float4 xv = *(float4*)&s_in[256*j + l*4];
      acc0 += DOT4(wA0[j], xv); acc1 += DOT4(wA1[j], xv);
    }

    // ---- A3: poll h2(t-1) record (hidden partly under A2's flight) ----
    if (t > 0){
      const u32x4* p2 = rh2 + pprev*512 + tid;
      u32x4 b;
      for(;;){
        b = ld16(p2);
        if (b.z >= (unsigned)t) break;
        __builtin_amdgcn_s_sleep(1);
      }
      *(float2*)&s_in[1536 + 2*tid] =
          make_float2(__uint_as_float(b.x), __uint_as_float(b.y));
    }
    __syncthreads();

    // ---- A4: wave0: y(t-1) dot + publish ry + out; all: WCL dot + pB ----
    if (t > 0 && w == 0){
      float y0 = 0.f, y1 = 0.f;
      #pragma unroll
      for (int i = 0; i < 4; i++){
        float4 xv = *(float4*)&s_in[1536 + 256*i + l*4];
        float4 w0 = *(float4*)&wy[256*i + l*4];
        float4 w1 = *(float4*)&wy[1024 + 256*i + l*4];
        y0 += DOT4(w0, xv); y1 += DOT4(w1, xv);
      }
      #pragma unroll
      for (int mk = 32; mk; mk >>= 1){
        y0 += __shfl_xor(y0, mk); y1 += __shfl_xor(y1, mk);
      }
      if (l == 0){
        y0 += bl0; y1 += bl1;
        *(float2*)&out[(size_t)(t-1)*512 + wid*2] = make_float2(y0, y1);
        u32x4 rec;
        rec.x = __float_as_uint(y0); rec.y = __float_as_uint(y1);
        rec.z = (unsigned)t; rec.w = 0u;
        st16(ry + pcur*256 + wid, rec);
      }
    }
    #pragma unroll
    for (int k = 0; k < 4; k++){
      float4 xv = *(float4*)&s_in[1536 + 256*k + l*4];
      float4 u0 = *(float4*)&wa[o0*1024 + 256*k + l*4];
      float4 u1 = *(float4*)&wa[o1*1024 + 256*k + l*4];
      acc0 += DOT4(u0, xv); acc1 += DOT4(u1, xv);
    }
    #pragma unroll
    for (int mk = 32; mk; mk >>= 1){
      acc0 += __shfl_xor(acc0, mk); acc1 += __shfl_xor(acc1, mk);
    }
    if (l == 0){ s_part[o0] = acc0; s_part[o1] = acc1; }

    // pB: precompute gates2's h2-dependent half (h2 in s_in[1536,2560))
    float pB0, pB1;
    {
      float4 xv = *(float4*)&s_in[1536 + l*4];
      pB0 = DOT4(wB0[4], xv); pB1 = DOT4(wB1[4], xv);
      #pragma unroll
      for (int k = 0; k < 3; k++){
        float4 x2 = *(float4*)&s_in[1536 + 256 + 256*k + l*4];
        float4 u0 = *(float4*)&wb[o0*768 + 256*k + l*4];
        float4 u1 = *(float4*)&wb[o1*768 + 256*k + l*4];
        pB0 += DOT4(u0, x2); pB1 += DOT4(u1, x2);
      }
    }
    __syncthreads();

    // ---- A5: publish BASE-GATE records (no lse wait!) ----
    if (w == 0 && l < 16){
      float sum = s_part[l] + biasAreg;
      if (t > 0) sum += bE2reg;
      float gi = __shfl(sum, (l & 3));
      float gf = __shfl(sum, 4 + (l & 3));
      float gg = __shfl(sum, 8 + (l & 3));
      float go = __shfl(sum, 12 + (l & 3));
      if (l < 4){
        u32x4 rA, rB;
        rA.x = __float_as_uint(gi); rA.y = __float_as_uint(gf);
        rA.z = __float_as_uint(gg); rA.w = need;
        rB.x = __float_as_uint(go); rB.y = __float_as_uint(s_c1[l]);
        rB.z = need; rB.w = 0u;
        int base = pcur*2048 + (wid*4 + l)*2;
        st16(rg1 + base,     rA);
        st16(rg1 + base + 1, rB);
      }
    }

    // ---- B1: wave0 poll ry->lse; all threads poll their 4 base recs ----
    if (w == 0 && t > 0){
      const u32x4* pyr = ry + pcur*256 + 4*l;
      u32x4 q0, q1, q2, q3;
      for(;;){
        ld16x4(pyr, q0, q1, q2, q3);
        if (q0.z >= (unsigned)t && q1.z >= (unsigned)t &&
            q2.z >= (unsigned)t && q3.z >= (unsigned)t) break;
        __builtin_amdgcn_s_sleep(1);
      }
      float v0 = __uint_as_float(q0.x), v1 = __uint_as_float(q0.y);
      float v2 = __uint_as_float(q1.x), v3 = __uint_as_float(q1.y);
      float v4 = __uint_as_float(q2.x), v5 = __uint_as_float(q2.y);
      float v6 = __uint_as_float(q3.x), v7 = __uint_as_float(q3.y);
      float m0 = fmaxf(fmaxf(fmaxf(v0,v1), fmaxf(v2,v3)),
                       fmaxf(fmaxf(v4,v5), fmaxf(v6,v7)));
      #pragma unroll
      for (int mk = 32; mk; mk >>= 1) m0 = fmaxf(m0, __shfl_xor(m0, mk));
      float s = expf(v0-m0)+expf(v1-m0)+expf(v2-m0)+expf(v3-m0)
              + expf(v4-m0)+expf(v5-m0)+expf(v6-m0)+expf(v7-m0);
      #pragma unroll
      for (int mk = 32; mk; mk >>= 1) s += __shfl_xor(s, mk);
      if (l == 0) s_lse[0] = m0 + logf(s);
    }
    u32x4 r0, r1, r2, r3;
    {
      const u32x4* pg = rg1 + pcur*2048 + 4*tid;
      for(;;){
        ld16x4(pg, r0, r1, r2, r3);
        if (r0.w >= need && r1.z >= need &&
            r2.w >= need && r3.z >= need) break;
        __builtin_amdgcn_s_sleep(1);
      }
    }
    __syncthreads();

    // ---- B1b: finalize h1 elements {2tid, 2tid+1} locally ----
    {
      float lse = s_lse[0];     // broadcast read (valid only for t>0)
      float i0 = __uint_as_float(r0.x), f0 = __uint_as_float(r0.y);
      float g0 = __uint_as_float(r0.z);
      float oo0 = __uint_as_float(r1.x), cp0 = __uint_as_float(r1.y);
      float i1 = __uint_as_float(r2.x), f1 = __uint_as_float(r2.y);
      float g1 = __uint_as_float(r2.z);
      float oo1 = __uint_as_float(r3.x), cp1 = __uint_as_float(r3.y);
      if (t > 0){
        i0 -= dE0.x*lse; f0 -= dE0.y*lse; g0 -= dE0.z*lse; oo0 -= dE0.w*lse;
        i1 -= dE1.x*lse; f1 -= dE1.y*lse; g1 -= dE1.z*lse; oo1 -= dE1.w*lse;
      }
      float cn0 = sigm(f0)*cp0 + sigm(i0)*tanhf(g0);
      float h0  = sigm(oo0)*tanhf(cn0);
      float cn1 = sigm(f1)*cp1 + sigm(i1)*tanhf(g1);
      float h1v = sigm(oo1)*tanhf(cn1);
      s_in[512 + 2*tid]     = h0;
      s_in[512 + 2*tid + 1] = h1v;
      if ((tid >> 1) == wid){           // owner: stash c_new for next record
        s_c1[2*(tid & 1)]     = cn0;
        s_c1[2*(tid & 1) + 1] = cn1;
      }
    }
    __syncthreads();

    // ---- B2: gates2 dot: regs j=0..3 on h1 + precomputed pB ----
    float b0 = pB0, b1 = pB1;
    #pragma unroll
    for (int j = 0; j < 4; j++){
      float4 xv = *(float4*)&s_in[512 + 256*j + l*4];
      b0 += DOT4(wB0[j], xv); b1 += DOT4(wB1[j], xv);
    }
    #pragma unroll
    for (int mk = 32; mk; mk >>= 1){
      b0 += __shfl_xor(b0, mk); b1 += __shfl_xor(b1, mk);
    }
    if (l == 0){ s_part[o0] = b0; s_part[o1] = b1; }
    __syncthreads();

    // ---- B3: finalize h2 (wave0, producer-owned c2), publish rh2 ----
    if (w == 0){
      float hn = 0.f;
      if (l < 16){
        float sum = s_part[l] + biasBreg;
        float gi = __shfl(sum, (l & 3));
        float gf = __shfl(sum, 4 + (l & 3));
        float gg = __shfl(sum, 8 + (l & 3));
        float go = __shfl(sum, 12 + (l & 3));
        if (l < 4){
          float cn = sigm(gf)*c2 + sigm(gi)*tanhf(gg);
          c2 = cn;
          hn = sigm(go)*tanhf(cn);
        }
      }
      float g0 = __shfl(hn, 2*(l & 1));
      float g1 = __shfl(hn, 2*(l & 1) + 1);
      if (l < 2){
        u32x4 rec;
        rec.x = __float_as_uint(g0); rec.y = __float_as_uint(g1);
        rec.z = need; rec.w = 0u;
        st16(rh2 + pcur*512 + wid*2 + l, rec);
      }
    }
  }

  // ===== tail: y(T-1) from rh2[(T-1)&1] records =====
  {
    const u32x4* p2 = rh2 + ((T_STEPS - 1) & 1)*512 + tid;
    u32x4 b;
    for(;;){
      b = ld16(p2);
      if (b.z >= (unsigned)T_STEPS) break;
      __builtin_amdgcn_s_sleep(1);
    }
    *(float2*)&s_in[1536 + 2*tid] =
        make_float2(__uint_as_float(b.x), __uint_as_float(b.y));
  }
  __syncthreads();
  if (w == 0){
    float y0 = 0.f, y1 = 0.f;
    #pragma unroll
    for (int i = 0; i < 4; i++){
      float4 xv = *(float4*)&s_in[1536 + 256*i + l*4];
      float4 w0 = *(float4*)&wy[256*i + l*4];
      float4 w1 = *(float4*)&wy[1024 + 256*i + l*4];
      y0 += DOT4(w0, xv); y1 += DOT4(w1, xv);
    }
    #pragma unroll
    for (int mk = 32; mk; mk >>= 1){
      y0 += __shfl_xor(y0, mk); y1 += __shfl_xor(y1, mk);
    }
    if (l == 0)
      *(float2*)&out[(size_t)(T_STEPS-1)*512 + wid*2] =
          make_float2(y0 + bl0, y1 + bl1);
  }
}

// ---------------------------------------------------------------------------
extern "C" void kernel_launch(void* const* d_in, const int* in_sizes, int n_in,
                              void* d_out, int out_size, void* d_ws, size_t ws_size,
                              hipStream_t stream)
{
  const float* x    = (const float*)d_in[0];
  const float* Ws   = (const float*)d_in[1];
  const float* bs   = (const float*)d_in[2];
  const float* Wih1 = (const float*)d_in[3];
  const float* Whh1 = (const float*)d_in[4];
  const float* bih1 = (const float*)d_in[5];
  const float* bhh1 = (const float*)d_in[6];
  const float* Wih2 = (const float*)d_in[7];
  const float* Whh2 = (const float*)d_in[8];
  const float* bih2 = (const float*)d_in[9];
  const float* bhh2 = (const float*)d_in[10];
  const float* Wl   = (const float*)d_in[11];
  const float* bl   = (const float*)d_in[12];
  const float* Wm   = (const float*)d_in[13];
  const float* bm   = (const float*)d_in[14];
  char* wsb  = (char*)d_ws;
  float* out = (float*)d_out;

  // zero records (seq=0 < any need) -- fresh each call / graph replay
  hipMemsetAsync(wsb, 0, WS_ZERO_BYTES, stream);

  feat_kernel<<<256, 512, 0, stream>>>(x, Ws, bs, (float*)(wsb + WS_FEAT));
  lstm_persist<<<NWG, 512, SMEM_BYTES, stream>>>(
      Wih1, Whh1, Wih2, Whh2, Wl, Wm,
      bih1, bhh1, bih2, bhh2, bl, bm, wsb, out);
  ls_kernel<<<T_STEPS, 64, 0, stream>>>(out);
}

// Round 13
// 31303.073 us; speedup vs baseline: 2.1098x; 2.1098x over previous
//
#include <hip/hip_runtime.h>
#include <math.h>

// ---------------------------------------------------------------------------
// LSTM_FEAT_2: T=4096 sequential 2-layer LSTM + log-softmax feedback.
// R13 = R11 (25.1ms champion; R12's deferred-lse records REFUTED: 4x record
// volume + 64B all-fanout polls -> contention storm, 66ms) + 3 safe edits:
//  1) pipelined 2-deep record polls (two loads in flight, vmcnt(1) checks)
//     -> discovery period RT -> RT/2 on the rh2 and rh1 gaps;
//  2) feat(t+1) staged under the rh1 gap (load issued before the poll);
//     phase A1 and its __syncthreads deleted (lifetime-checked);
//  3) sleeps dropped from polls (they self-pace at ~RT/2).
//
// Math (unchanged, verified R7-R12):
//   feat_t = Ws@x_t + bs                       (startup kernel)
//   gates1 = [Wih1s|Whh1]@[feat;h1] + WCL@h2 + biasA [+ biasE2 - rsWC*lse]
//     WCL=(Wih1e@Wm)@Wl, biasE2=Wih1e@bm+WC@bl, rsWC=rowsum(WC)
//   gates2 = [Wih2|Whh2]@[h1;h2] + biasB
//   y_t    = Wl@h2_t + bl -> d_out ; post-pass: out = log_softmax(out)
// ---------------------------------------------------------------------------

#define T_STEPS 4096
#define NWG 256

typedef unsigned u32x4 __attribute__((ext_vector_type(4)));

// ws layout (bytes)
#define WS_RH1   0            // u32x4[2][512]: h1 records {h,h,seq,0} (16KB)
#define WS_RH2   16384        // u32x4[2][512]: h2 records (16KB)
#define WS_RY    32768        // u32x4[2][256]: y records {y0,y1,seq,0} (8KB)
#define WS_ZERO_BYTES 40960
#define WS_FEAT  40960        // float[4096][512] -> end ~8.4MB

// dynamic LDS partition (floats)
#define OFF_WA 2560           // s_in[2560] | wa[16][1024] | wb[16][768] | wy[2][1024]
#define OFF_WB 18944
#define OFF_WY 31232
#define SMEM_FLOATS 33280
#define SMEM_BYTES  (SMEM_FLOATS*4)

#define PIN4(v) asm volatile("" : "+v"((v).x), "+v"((v).y), "+v"((v).z), "+v"((v).w))
#define PIN1(v) asm volatile("" : "+v"(v))
#define FMA4(acc,s,v4) {(acc).x += (s)*(v4).x; (acc).y += (s)*(v4).y; (acc).z += (s)*(v4).z; (acc).w += (s)*(v4).w;}
#define DOT4(a,b) ((a).x*(b).x + (a).y*(b).y + (a).z*(b).z + (a).w*(b).w)

__device__ __forceinline__ void ld16x4(const u32x4* p, u32x4& r0, u32x4& r1,
                                       u32x4& r2, u32x4& r3){
  asm volatile("global_load_dwordx4 %0, %4, off sc0 sc1\n\t"
               "global_load_dwordx4 %1, %4, off offset:16 sc0 sc1\n\t"
               "global_load_dwordx4 %2, %4, off offset:32 sc0 sc1\n\t"
               "global_load_dwordx4 %3, %4, off offset:48 sc0 sc1\n\t"
               "s_waitcnt vmcnt(0)"
               : "=&v"(r0), "=&v"(r1), "=&v"(r2), "=&v"(r3)
               : "v"(p) : "memory");
}
__device__ __forceinline__ void st16(u32x4* p, u32x4 v){
  asm volatile("global_store_dwordx4 %0, %1, off sc0 sc1"
               :: "v"(p), "v"(v) : "memory");
}
// pipelined 2-deep poll: two loads in flight, check one per vmcnt(1).
// Exits with vmcnt fully drained (safe for register reuse + later ds ops).
__device__ __forceinline__ u32x4 pollrec(const u32x4* p, unsigned need){
  u32x4 a, b;
  asm volatile("global_load_dwordx4 %0, %1, off sc0 sc1" : "=v"(a) : "v"(p));
  for(;;){
    asm volatile("global_load_dwordx4 %0, %1, off sc0 sc1" : "=v"(b) : "v"(p));
    asm volatile("s_waitcnt vmcnt(1)" : "+v"(a) :: "memory");
    if (a.z >= need) break;
    asm volatile("global_load_dwordx4 %0, %1, off sc0 sc1" : "=v"(a) : "v"(p));
    asm volatile("s_waitcnt vmcnt(1)" : "+v"(b) :: "memory");
    if (b.z >= need){ a = b; break; }
  }
  asm volatile("s_waitcnt vmcnt(0)" ::: "memory");
  return a;
}
__device__ __forceinline__ float sigm(float x){ return 1.0f/(1.0f+expf(-x)); }

// ---------------------------------------------------------------------------
// startup: feat[t][k] = Ws[k]·x[t] + bs[k]
__global__ __launch_bounds__(512) void feat_kernel(
    const float* __restrict__ x, const float* __restrict__ Ws,
    const float* __restrict__ bs, float* __restrict__ feat)
{
  __shared__ float s_x[16][360];
  __shared__ float s_w[512][20];
  const int bid = blockIdx.x, tid = threadIdx.x;
  const int t0 = bid * 16;
  for (int tt = 0; tt < 16; tt++)
    if (tid < 360) s_x[tt][tid] = x[(t0+tt)*360 + tid];
  float acc[16];
  #pragma unroll
  for (int i = 0; i < 16; i++) acc[i] = 0.f;
  for (int d0 = 0; d0 < 360; d0 += 16){
    const int dn = (360 - d0 < 16) ? (360 - d0) : 16;
    __syncthreads();
    if (dn == 16){
      #pragma unroll
      for (int c4 = 0; c4 < 4; c4++)
        *(float4*)&s_w[tid][c4*4] = *(const float4*)&Ws[tid*360 + d0 + c4*4];
    } else {
      for (int c = 0; c < dn; c++) s_w[tid][c] = Ws[tid*360 + d0 + c];
    }
    __syncthreads();
    for (int c = 0; c < dn; c++){
      float wv = s_w[tid][c];
      #pragma unroll
      for (int tt = 0; tt < 16; tt++) acc[tt] += wv * s_x[tt][d0 + c];
    }
  }
  for (int tt = 0; tt < 16; tt++)
    feat[(t0+tt)*512 + tid] = acc[tt] + bs[tid];
}

// ---------------------------------------------------------------------------
// post-pass: out[t] = out[t] - logsumexp(out[t])  (in place)
__global__ __launch_bounds__(64) void ls_kernel(float* __restrict__ out)
{
  const int t = blockIdx.x, l = threadIdx.x;
  float v[8];
  #pragma unroll
  for (int i = 0; i < 8; i++) v[i] = out[t*512 + l*8 + i];
  float m0 = v[0];
  #pragma unroll
  for (int i = 1; i < 8; i++) m0 = fmaxf(m0, v[i]);
  #pragma unroll
  for (int mk = 32; mk; mk >>= 1) m0 = fmaxf(m0, __shfl_xor(m0, mk));
  float s = 0.f;
  #pragma unroll
  for (int i = 0; i < 8; i++) s += expf(v[i] - m0);
  #pragma unroll
  for (int mk = 32; mk; mk >>= 1) s += __shfl_xor(s, mk);
  float lse = m0 + logf(s);
  #pragma unroll
  for (int i = 0; i < 8; i++) out[t*512 + l*8 + i] = v[i] - lse;
}

// ---------------------------------------------------------------------------
// persistent kernel: 256 wgs x 512 thr (8 waves), 1 wg/CU via 133KB LDS.
// Wave w owns gate rows {2w,2w+1}; lane l owns f4 col-chunks (bank-clean).
// s_in layout (persistent): feat[0,512) | h1[512,1536) | h2[1536,2560).
__global__ __launch_bounds__(512, 1) void lstm_persist(
    const float* __restrict__ Wih1, const float* __restrict__ Whh1,
    const float* __restrict__ Wih2, const float* __restrict__ Whh2,
    const float* __restrict__ Wl,   const float* __restrict__ Wm,
    const float* __restrict__ bih1, const float* __restrict__ bhh1,
    const float* __restrict__ bih2, const float* __restrict__ bhh2,
    const float* __restrict__ blp,  const float* __restrict__ bmp,
    char* __restrict__ wsb, float* __restrict__ out)
{
  extern __shared__ float smem[];
  float* s_in = smem;               // feat | h1 | h2 (persistent regions)
  float* wa   = smem + OFF_WA;      // [16][1024] = WCL rows
  float* wb   = smem + OFF_WB;      // [16][768]  = Whh2 cols 256..1023 (init: WCtmp)
  float* wy   = smem + OFF_WY;      // [2][1024]  = Wl rows wid*2, wid*2+1
  __shared__ float s_part[16];
  __shared__ float s_sums[32];

  u32x4* rh1 = (u32x4*)(wsb + WS_RH1);   // [2][512]
  u32x4* rh2 = (u32x4*)(wsb + WS_RH2);   // [2][512]
  u32x4* ry  = (u32x4*)(wsb + WS_RY);    // [2][256]
  const float* featp = (const float*)(wsb + WS_FEAT);

  const int wid = blockIdx.x, tid = threadIdx.x;
  const int w = tid >> 6, l = tid & 63;
  const int o0 = 2*w, o1 = 2*w + 1;
  const int rA0 = (o0 >> 2)*1024 + wid*4 + (o0 & 3);
  const int rA1 = (o1 >> 2)*1024 + wid*4 + (o1 & 3);

  // ===== init 1: stage this wg's 16 Wih1e rows (16x128) into s_in =====
  for (int idx = tid; idx < 2048; idx += 512){
    int o = idx >> 7, e = idx & 127;
    int r = (o >> 2)*1024 + wid*4 + (o & 3);
    s_in[idx] = Wih1[r*640 + 512 + e];
  }
  __syncthreads();

  // ===== init 2: WCtmp = Wih1e @ Wm  (16x512) -> wb area =====
  {
    float4 a00 = {0,0,0,0}, a01 = a00, a10 = a00, a11 = a00;
    for (int e = 0; e < 128; e++){
      float w0e = s_in[o0*128 + e], w1e = s_in[o1*128 + e];
      float4 m0 = *(const float4*)&Wm[e*512 + l*4];
      float4 m1 = *(const float4*)&Wm[e*512 + l*4 + 256];
      FMA4(a00, w0e, m0); FMA4(a01, w0e, m1);
      FMA4(a10, w1e, m0); FMA4(a11, w1e, m1);
    }
    *(float4*)&wb[o0*512 + l*4]       = a00;
    *(float4*)&wb[o0*512 + l*4 + 256] = a01;
    *(float4*)&wb[o1*512 + l*4]       = a10;
    *(float4*)&wb[o1*512 + l*4 + 256] = a11;
  }
  __syncthreads();

  // ===== init 3: WCL = WCtmp @ Wl (16x1024) -> wa; WC@bl piggyback =====
  {
    float4 c00={0,0,0,0}, c01=c00, c02=c00, c03=c00;
    float4 c10=c00, c11=c00, c12=c00, c13=c00;
    float wl0=0.f, wl1=0.f;
    for (int m = 0; m < 512; m++){
      float t0 = wb[o0*512 + m], t1 = wb[o1*512 + m];
      float blm = blp[m];
      wl0 += t0*blm; wl1 += t1*blm;
      float4 q0 = *(const float4*)&Wl[m*1024 + l*4];
      float4 q1 = *(const float4*)&Wl[m*1024 + l*4 + 256];
      float4 q2 = *(const float4*)&Wl[m*1024 + l*4 + 512];
      float4 q3 = *(const float4*)&Wl[m*1024 + l*4 + 768];
      FMA4(c00,t0,q0); FMA4(c01,t0,q1); FMA4(c02,t0,q2); FMA4(c03,t0,q3);
      FMA4(c10,t1,q0); FMA4(c11,t1,q1); FMA4(c12,t1,q2); FMA4(c13,t1,q3);
    }
    *(float4*)&wa[o0*1024 + l*4      ] = c00;
    *(float4*)&wa[o0*1024 + l*4 + 256] = c01;
    *(float4*)&wa[o0*1024 + l*4 + 512] = c02;
    *(float4*)&wa[o0*1024 + l*4 + 768] = c03;
    *(float4*)&wa[o1*1024 + l*4      ] = c10;
    *(float4*)&wa[o1*1024 + l*4 + 256] = c11;
    *(float4*)&wa[o1*1024 + l*4 + 512] = c12;
    *(float4*)&wa[o1*1024 + l*4 + 768] = c13;
    if (l == 0){ s_sums[w*2+0] = wl0; s_sums[w*2+1] = wl1; }
  }
  __syncthreads();

  // ===== init 4: per-row bias regs (wave 0); rsWC from resident WCtmp =====
  float biasAreg=0.f, biasBreg=0.f, bE2reg=0.f, rsReg=0.f;
  float bl0=0.f, bl1=0.f, c1=0.f, c2=0.f;
  if (w == 0 && l < 16){
    int r = (l >> 2)*1024 + wid*4 + (l & 3);
    biasAreg = bih1[r] + bhh1[r];
    biasBreg = bih2[r] + bhh2[r];
    float acc = s_sums[(l>>1)*2 + (l&1)];     // WC@bl for this row
    for (int e = 0; e < 128; e++) acc += s_in[l*128 + e] * bmp[e];
    bE2reg = acc;
    float rsum = 0.f;
    for (int m = 0; m < 512; m += 4){
      float4 v = *(float4*)&wb[l*512 + m];    // WCtmp row l (still resident)
      rsum += v.x + v.y + v.z + v.w;
    }
    rsReg = rsum;
  }
  if (w == 0 && l == 0){ bl0 = blp[wid*2]; bl1 = blp[wid*2 + 1]; }
  __syncthreads();     // init4's s_in/wb reads done before overwrite below

  // ===== init 5: zero h1/h2; stage feat(0); LDS weights wb, wy ====
  for (int idx = tid; idx < 2048; idx += 512) s_in[512 + idx] = 0.f;
  if (tid < 256)
    *(float2*)&s_in[tid*2] = *(const float2*)&featp[tid*2];
  for (int o = 0; o < 16; o++){
    int r = (o >> 2)*1024 + wid*4 + (o & 3);
    for (int c = tid; c < 768; c += 512)
      wb[o*768 + c] = Whh2[r*1024 + 256 + c];
  }
  for (int idx = tid; idx < 2048; idx += 512){
    int row = idx >> 10, c = idx & 1023;
    wy[idx] = Wl[(wid*2 + row)*1024 + c];
  }

  // ===== init 6: pinned register weights (88 floats/thread) =====
  float4 wA0[6], wA1[6], wB0[5], wB1[5];
  #pragma unroll
  for (int j = 0; j < 6; j++){
    int c = 256*j + l*4;
    wA0[j] = (c < 512) ? *(const float4*)&Wih1[rA0*640 + c]
                       : *(const float4*)&Whh1[rA0*1024 + c - 512];
    wA1[j] = (c < 512) ? *(const float4*)&Wih1[rA1*640 + c]
                       : *(const float4*)&Whh1[rA1*1024 + c - 512];
  }
  #pragma unroll
  for (int j = 0; j < 5; j++){
    int c = 256*j + l*4;
    wB0[j] = (c < 1024) ? *(const float4*)&Wih2[rA0*1024 + c]
                        : *(const float4*)&Whh2[rA0*1024 + c - 1024];
    wB1[j] = (c < 1024) ? *(const float4*)&Wih2[rA1*1024 + c]
                        : *(const float4*)&Whh2[rA1*1024 + c - 1024];
  }
  #pragma unroll
  for (int j = 0; j < 6; j++){ PIN4(wA0[j]); PIN4(wA1[j]); }
  #pragma unroll
  for (int j = 0; j < 5; j++){ PIN4(wB0[j]); PIN4(wB1[j]); }
  PIN1(biasAreg); PIN1(biasBreg); PIN1(bE2reg); PIN1(rsReg);
  PIN1(bl0); PIN1(bl1);
  __syncthreads();

  // ===== main loop =====
  for (int t = 0; t < T_STEPS; t++){
    const int pprev = (t + 1) & 1;       // parity of step t-1
    const int pcur  = t & 1;             // parity of step t

    // ---- A2: partial gates1 (feat+h1, reg weights). No loop-top sync:
    //      feat(t) staged during B1(t-1); h1(t-1) in LDS from B1(t-1). ----
    float acc0 = 0.f, acc1 = 0.f;
    #pragma unroll
    for (int j = 0; j < 6; j++){
      float4 xv = *(float4*)&s_in[256*j + l*4];
      acc0 += DOT4(wA0[j], xv); acc1 += DOT4(wA1[j], xv);
    }

    // ---- A3: pipelined poll h2(t-1) record ----
    if (t > 0){
      u32x4 b = pollrec(rh2 + pprev*512 + tid, (unsigned)t);
      *(float2*)&s_in[1536 + 2*tid] =
          make_float2(__uint_as_float(b.x), __uint_as_float(b.y));
    }
    __syncthreads();

    // ---- A4: wave0: y(t-1) dot + publish ry + out; all: WCL dot + pB ----
    if (t > 0 && w == 0){
      float y0 = 0.f, y1 = 0.f;
      #pragma unroll
      for (int i = 0; i < 4; i++){
        float4 xv = *(float4*)&s_in[1536 + 256*i + l*4];
        float4 w0 = *(float4*)&wy[256*i + l*4];
        float4 w1 = *(float4*)&wy[1024 + 256*i + l*4];
        y0 += DOT4(w0, xv); y1 += DOT4(w1, xv);
      }
      #pragma unroll
      for (int mk = 32; mk; mk >>= 1){
        y0 += __shfl_xor(y0, mk); y1 += __shfl_xor(y1, mk);
      }
      if (l == 0){
        y0 += bl0; y1 += bl1;
        *(float2*)&out[(size_t)(t-1)*512 + wid*2] = make_float2(y0, y1);
        u32x4 rec;
        rec.x = __float_as_uint(y0); rec.y = __float_as_uint(y1);
        rec.z = (unsigned)t; rec.w = 0u;
        st16(ry + pcur*256 + wid, rec);
      }
    }
    #pragma unroll
    for (int k = 0; k < 4; k++){
      float4 xv = *(float4*)&s_in[1536 + 256*k + l*4];
      float4 u0 = *(float4*)&wa[o0*1024 + 256*k + l*4];
      float4 u1 = *(float4*)&wa[o1*1024 + 256*k + l*4];
      acc0 += DOT4(u0, xv); acc1 += DOT4(u1, xv);
    }
    #pragma unroll
    for (int mk = 32; mk; mk >>= 1){
      acc0 += __shfl_xor(acc0, mk); acc1 += __shfl_xor(acc1, mk);
    }
    if (l == 0){ s_part[o0] = acc0; s_part[o1] = acc1; }

    // pB: precompute gates2's h2-dependent half (h2 in s_in[1536,2560))
    float pB0, pB1;
    {
      float4 xv = *(float4*)&s_in[1536 + l*4];
      pB0 = DOT4(wB0[4], xv); pB1 = DOT4(wB1[4], xv);
      #pragma unroll
      for (int k = 0; k < 3; k++){
        float4 x2 = *(float4*)&s_in[1536 + 256 + 256*k + l*4];
        float4 u0 = *(float4*)&wb[o0*768 + 256*k + l*4];
        float4 u1 = *(float4*)&wb[o1*768 + 256*k + l*4];
        pB0 += DOT4(u0, x2); pB1 += DOT4(u1, x2);
      }
    }
    __syncthreads();

    // ---- A5: finalize (wave0): batched lse poll, gates, publish rh1 ----
    if (w == 0){
      float lse = 0.f;
      if (t > 0){
        const u32x4* pyr = ry + pcur*256 + 4*l;
        u32x4 r0, r1, r2, r3;
        for(;;){
          ld16x4(pyr, r0, r1, r2, r3);
          if (r0.z >= (unsigned)t && r1.z >= (unsigned)t &&
              r2.z >= (unsigned)t && r3.z >= (unsigned)t) break;
        }
        float v0 = __uint_as_float(r0.x), v1 = __uint_as_float(r0.y);
        float v2 = __uint_as_float(r1.x), v3 = __uint_as_float(r1.y);
        float v4 = __uint_as_float(r2.x), v5 = __uint_as_float(r2.y);
        float v6 = __uint_as_float(r3.x), v7 = __uint_as_float(r3.y);
        float m0 = fmaxf(fmaxf(fmaxf(v0,v1), fmaxf(v2,v3)),
                         fmaxf(fmaxf(v4,v5), fmaxf(v6,v7)));
        #pragma unroll
        for (int mk = 32; mk; mk >>= 1) m0 = fmaxf(m0, __shfl_xor(m0, mk));
        float s = expf(v0-m0)+expf(v1-m0)+expf(v2-m0)+expf(v3-m0)
                + expf(v4-m0)+expf(v5-m0)+expf(v6-m0)+expf(v7-m0);
        #pragma unroll
        for (int mk = 32; mk; mk >>= 1) s += __shfl_xor(s, mk);
        lse = m0 + logf(s);
      }
      float hn = 0.f;
      if (l < 16){
        float sum = s_part[l] + biasAreg;
        if (t > 0) sum += bE2reg - rsReg*lse;
        float gi = __shfl(sum, (l & 3));
        float gf = __shfl(sum, 4 + (l & 3));
        float gg = __shfl(sum, 8 + (l & 3));
        float go = __shfl(sum, 12 + (l & 3));
        if (l < 4){
          float cn = sigm(gf)*c1 + sigm(gi)*tanhf(gg);
          c1 = cn;
          hn = sigm(go)*tanhf(cn);
        }
      }
      float g0 = __shfl(hn, 2*(l & 1));
      float g1 = __shfl(hn, 2*(l & 1) + 1);
      if (l < 2){
        u32x4 rec;
        rec.x = __float_as_uint(g0); rec.y = __float_as_uint(g1);
        rec.z = (unsigned)(t + 1); rec.w = 0u;
        st16(rh1 + pcur*512 + wid*2 + l, rec);
      }
    }

    // ---- B1: issue feat(t+1) load; pipelined poll rh1; stage both ----
    float2 fv;
    if (tid < 256){
      int tn = (t + 1 < T_STEPS) ? (t + 1) : t;
      fv = *(const float2*)&featp[(size_t)tn*512 + tid*2];
    }
    {
      u32x4 a = pollrec(rh1 + pcur*512 + tid, (unsigned)(t + 1));
      *(float2*)&s_in[512 + 2*tid] =
          make_float2(__uint_as_float(a.x), __uint_as_float(a.y));
    }
    if (tid < 256) *(float2*)&s_in[tid*2] = fv;
    __syncthreads();

    // ---- B2: gates2 dot: regs j=0..3 on h1 + precomputed pB ----
    float b0 = pB0, b1 = pB1;
    #pragma unroll
    for (int j = 0; j < 4; j++){
      float4 xv = *(float4*)&s_in[512 + 256*j + l*4];
      b0 += DOT4(wB0[j], xv); b1 += DOT4(wB1[j], xv);
    }
    #pragma unroll
    for (int mk = 32; mk; mk >>= 1){
      b0 += __shfl_xor(b0, mk); b1 += __shfl_xor(b1, mk);
    }
    if (l == 0){ s_part[o0] = b0; s_part[o1] = b1; }
    __syncthreads();

    // ---- B3: finalize h2 (wave0), publish rh2 ----
    if (w == 0){
      float hn = 0.f;
      if (l < 16){
        float sum = s_part[l] + biasBreg;
        float gi = __shfl(sum, (l & 3));
        float gf = __shfl(sum, 4 + (l & 3));
        float gg = __shfl(sum, 8 + (l & 3));
        float go = __shfl(sum, 12 + (l & 3));
        if (l < 4){
          float cn = sigm(gf)*c2 + sigm(gi)*tanhf(gg);
          c2 = cn;
          hn = sigm(go)*tanhf(cn);
        }
      }
      float g0 = __shfl(hn, 2*(l & 1));
      float g1 = __shfl(hn, 2*(l & 1) + 1);
      if (l < 2){
        u32x4 rec;
        rec.x = __float_as_uint(g0); rec.y = __float_as_uint(g1);
        rec.z = (unsigned)(t + 1); rec.w = 0u;
        st16(rh2 + pcur*512 + wid*2 + l, rec);
      }
    }
  }

  // ===== tail: y(T-1) from rh2[(T-1)&1] records =====
  {
    u32x4 b = pollrec(rh2 + ((T_STEPS - 1) & 1)*512 + tid, (unsigned)T_STEPS);
    *(float2*)&s_in[1536 + 2*tid] =
        make_float2(__uint_as_float(b.x), __uint_as_float(b.y));
  }
  __syncthreads();
  if (w == 0){
    float y0 = 0.f, y1 = 0.f;
    #pragma unroll
    for (int i = 0; i < 4; i++){
      float4 xv = *(float4*)&s_in[1536 + 256*i + l*4];
      float4 w0 = *(float4*)&wy[256*i + l*4];
      float4 w1 = *(float4*)&wy[1024 + 256*i + l*4];
      y0 += DOT4(w0, xv); y1 += DOT4(w1, xv);
    }
    #pragma unroll
    for (int mk = 32; mk; mk >>= 1){
      y0 += __shfl_xor(y0, mk); y1 += __shfl_xor(y1, mk);
    }
    if (l == 0)
      *(float2*)&out[(size_t)(T_STEPS-1)*512 + wid*2] =
          make_float2(y0 + bl0, y1 + bl1);
  }
}

// ---------------------------------------------------------------------------
extern "C" void kernel_launch(void* const* d_in, const int* in_sizes, int n_in,
                              void* d_out, int out_size, void* d_ws, size_t ws_size,
                              hipStream_t stream)
{
  const float* x    = (const float*)d_in[0];
  const float* Ws   = (const float*)d_in[1];
  const float* bs   = (const float*)d_in[2];
  const float* Wih1 = (const float*)d_in[3];
  const float* Whh1 = (const float*)d_in[4];
  const float* bih1 = (const float*)d_in[5];
  const float* bhh1 = (const float*)d_in[6];
  const float* Wih2 = (const float*)d_in[7];
  const float* Whh2 = (const float*)d_in[8];
  const float* bih2 = (const float*)d_in[9];
  const float* bhh2 = (const float*)d_in[10];
  const float* Wl   = (const float*)d_in[11];
  const float* bl   = (const float*)d_in[12];
  const float* Wm   = (const float*)d_in[13];
  const float* bm   = (const float*)d_in[14];
  char* wsb  = (char*)d_ws;
  float* out = (float*)d_out;

  // zero records (seq=0 < any need) -- fresh each call / graph replay
  hipMemsetAsync(wsb, 0, WS_ZERO_BYTES, stream);

  feat_kernel<<<256, 512, 0, stream>>>(x, Ws, bs, (float*)(wsb + WS_FEAT));
  lstm_persist<<<NWG, 512, SMEM_BYTES, stream>>>(
      Wih1, Whh1, Wih2, Whh2, Wl, Wm,
      bih1, bhh1, bih2, bhh2, bl, bm, wsb, out);
  ls_kernel<<<T_STEPS, 64, 0, stream>>>(out);
}

// Round 14
// 29642.819 us; speedup vs baseline: 2.2280x; 1.0560x over previous
//
#include <hip/hip_runtime.h>
#include <math.h>

// ---------------------------------------------------------------------------
// LSTM_FEAT_2: T=4096 sequential 2-layer LSTM + log-softmax feedback.
// R14 = R11 (25.1ms champion) + ONE isolated edit (R13's edit #2):
//   feat(t+1) staged under B1's rh1 poll gap; phase A1 + its __syncthreads
//   deleted; feat(0) staged at init.
// R13's other edits REVERTED: polls are R11's single-ld16 + s_sleep(1)
// pacing (R13's sleepless 2-deep polls raised FETCH 590->834MB and dur
// 25.1->31.3ms -- poll-rate contention slowed the producer stores; R8
// lesson re-confirmed).
//
// Math (unchanged, verified R7-R13):
//   feat_t = Ws@x_t + bs                       (startup kernel)
//   gates1 = [Wih1s|Whh1]@[feat;h1] + WCL@h2 + biasA [+ biasE2 - rsWC*lse]
//     WCL=(Wih1e@Wm)@Wl, biasE2=Wih1e@bm+WC@bl, rsWC=rowsum(WC)
//   gates2 = [Wih2|Whh2]@[h1;h2] + biasB
//   y_t    = Wl@h2_t + bl -> d_out ; post-pass: out = log_softmax(out)
// ---------------------------------------------------------------------------

#define T_STEPS 4096
#define NWG 256

typedef unsigned u32x4 __attribute__((ext_vector_type(4)));

// ws layout (bytes)
#define WS_RH1   0            // u32x4[2][512]: h1 records {h,h,seq,0} (16KB)
#define WS_RH2   16384        // u32x4[2][512]: h2 records (16KB)
#define WS_RY    32768        // u32x4[2][256]: y records {y0,y1,seq,0} (8KB)
#define WS_ZERO_BYTES 40960
#define WS_FEAT  40960        // float[4096][512] -> end ~8.4MB

// dynamic LDS partition (floats)
#define OFF_WA 2560           // s_in[2560] | wa[16][1024] | wb[16][768] | wy[2][1024]
#define OFF_WB 18944
#define OFF_WY 31232
#define SMEM_FLOATS 33280
#define SMEM_BYTES  (SMEM_FLOATS*4)

#define PIN4(v) asm volatile("" : "+v"((v).x), "+v"((v).y), "+v"((v).z), "+v"((v).w))
#define PIN1(v) asm volatile("" : "+v"(v))
#define FMA4(acc,s,v4) {(acc).x += (s)*(v4).x; (acc).y += (s)*(v4).y; (acc).z += (s)*(v4).z; (acc).w += (s)*(v4).w;}
#define DOT4(a,b) ((a).x*(b).x + (a).y*(b).y + (a).z*(b).z + (a).w*(b).w)

// coherent 16B transactional load/store (bypass L1/L2 -> LLC)
__device__ __forceinline__ u32x4 ld16(const u32x4* p){
  u32x4 r;
  asm volatile("global_load_dwordx4 %0, %1, off sc0 sc1\n\ts_waitcnt vmcnt(0)"
               : "=v"(r) : "v"(p) : "memory");
  return r;
}
// 4 contiguous records, ONE waitcnt (offset immediates)
__device__ __forceinline__ void ld16x4(const u32x4* p, u32x4& r0, u32x4& r1,
                                       u32x4& r2, u32x4& r3){
  asm volatile("global_load_dwordx4 %0, %4, off sc0 sc1\n\t"
               "global_load_dwordx4 %1, %4, off offset:16 sc0 sc1\n\t"
               "global_load_dwordx4 %2, %4, off offset:32 sc0 sc1\n\t"
               "global_load_dwordx4 %3, %4, off offset:48 sc0 sc1\n\t"
               "s_waitcnt vmcnt(0)"
               : "=&v"(r0), "=&v"(r1), "=&v"(r2), "=&v"(r3)
               : "v"(p) : "memory");
}
__device__ __forceinline__ void st16(u32x4* p, u32x4 v){
  asm volatile("global_store_dwordx4 %0, %1, off sc0 sc1"
               :: "v"(p), "v"(v) : "memory");
}
__device__ __forceinline__ float sigm(float x){ return 1.0f/(1.0f+expf(-x)); }

// ---------------------------------------------------------------------------
// startup: feat[t][k] = Ws[k]·x[t] + bs[k]
__global__ __launch_bounds__(512) void feat_kernel(
    const float* __restrict__ x, const float* __restrict__ Ws,
    const float* __restrict__ bs, float* __restrict__ feat)
{
  __shared__ float s_x[16][360];
  __shared__ float s_w[512][20];
  const int bid = blockIdx.x, tid = threadIdx.x;
  const int t0 = bid * 16;
  for (int tt = 0; tt < 16; tt++)
    if (tid < 360) s_x[tt][tid] = x[(t0+tt)*360 + tid];
  float acc[16];
  #pragma unroll
  for (int i = 0; i < 16; i++) acc[i] = 0.f;
  for (int d0 = 0; d0 < 360; d0 += 16){
    const int dn = (360 - d0 < 16) ? (360 - d0) : 16;
    __syncthreads();
    if (dn == 16){
      #pragma unroll
      for (int c4 = 0; c4 < 4; c4++)
        *(float4*)&s_w[tid][c4*4] = *(const float4*)&Ws[tid*360 + d0 + c4*4];
    } else {
      for (int c = 0; c < dn; c++) s_w[tid][c] = Ws[tid*360 + d0 + c];
    }
    __syncthreads();
    for (int c = 0; c < dn; c++){
      float wv = s_w[tid][c];
      #pragma unroll
      for (int tt = 0; tt < 16; tt++) acc[tt] += wv * s_x[tt][d0 + c];
    }
  }
  for (int tt = 0; tt < 16; tt++)
    feat[(t0+tt)*512 + tid] = acc[tt] + bs[tid];
}

// ---------------------------------------------------------------------------
// post-pass: out[t] = out[t] - logsumexp(out[t])  (in place)
__global__ __launch_bounds__(64) void ls_kernel(float* __restrict__ out)
{
  const int t = blockIdx.x, l = threadIdx.x;
  float v[8];
  #pragma unroll
  for (int i = 0; i < 8; i++) v[i] = out[t*512 + l*8 + i];
  float m0 = v[0];
  #pragma unroll
  for (int i = 1; i < 8; i++) m0 = fmaxf(m0, v[i]);
  #pragma unroll
  for (int mk = 32; mk; mk >>= 1) m0 = fmaxf(m0, __shfl_xor(m0, mk));
  float s = 0.f;
  #pragma unroll
  for (int i = 0; i < 8; i++) s += expf(v[i] - m0);
  #pragma unroll
  for (int mk = 32; mk; mk >>= 1) s += __shfl_xor(s, mk);
  float lse = m0 + logf(s);
  #pragma unroll
  for (int i = 0; i < 8; i++) out[t*512 + l*8 + i] = v[i] - lse;
}

// ---------------------------------------------------------------------------
// persistent kernel: 256 wgs x 512 thr (8 waves), 1 wg/CU via 133KB LDS.
// Wave w owns gate rows {2w,2w+1}; lane l owns f4 col-chunks (bank-clean).
// s_in layout (persistent): feat[0,512) | h1[512,1536) | h2[1536,2560).
__global__ __launch_bounds__(512, 1) void lstm_persist(
    const float* __restrict__ Wih1, const float* __restrict__ Whh1,
    const float* __restrict__ Wih2, const float* __restrict__ Whh2,
    const float* __restrict__ Wl,   const float* __restrict__ Wm,
    const float* __restrict__ bih1, const float* __restrict__ bhh1,
    const float* __restrict__ bih2, const float* __restrict__ bhh2,
    const float* __restrict__ blp,  const float* __restrict__ bmp,
    char* __restrict__ wsb, float* __restrict__ out)
{
  extern __shared__ float smem[];
  float* s_in = smem;               // feat | h1 | h2 (persistent regions)
  float* wa   = smem + OFF_WA;      // [16][1024] = WCL rows
  float* wb   = smem + OFF_WB;      // [16][768]  = Whh2 cols 256..1023 (init: WCtmp)
  float* wy   = smem + OFF_WY;      // [2][1024]  = Wl rows wid*2, wid*2+1
  __shared__ float s_part[16];
  __shared__ float s_sums[32];

  u32x4* rh1 = (u32x4*)(wsb + WS_RH1);   // [2][512]
  u32x4* rh2 = (u32x4*)(wsb + WS_RH2);   // [2][512]
  u32x4* ry  = (u32x4*)(wsb + WS_RY);    // [2][256]
  const float* featp = (const float*)(wsb + WS_FEAT);

  const int wid = blockIdx.x, tid = threadIdx.x;
  const int w = tid >> 6, l = tid & 63;
  const int o0 = 2*w, o1 = 2*w + 1;
  const int rA0 = (o0 >> 2)*1024 + wid*4 + (o0 & 3);
  const int rA1 = (o1 >> 2)*1024 + wid*4 + (o1 & 3);

  // ===== init 1: stage this wg's 16 Wih1e rows (16x128) into s_in =====
  for (int idx = tid; idx < 2048; idx += 512){
    int o = idx >> 7, e = idx & 127;
    int r = (o >> 2)*1024 + wid*4 + (o & 3);
    s_in[idx] = Wih1[r*640 + 512 + e];
  }
  __syncthreads();

  // ===== init 2: WCtmp = Wih1e @ Wm  (16x512) -> wb area =====
  {
    float4 a00 = {0,0,0,0}, a01 = a00, a10 = a00, a11 = a00;
    for (int e = 0; e < 128; e++){
      float w0e = s_in[o0*128 + e], w1e = s_in[o1*128 + e];
      float4 m0 = *(const float4*)&Wm[e*512 + l*4];
      float4 m1 = *(const float4*)&Wm[e*512 + l*4 + 256];
      FMA4(a00, w0e, m0); FMA4(a01, w0e, m1);
      FMA4(a10, w1e, m0); FMA4(a11, w1e, m1);
    }
    *(float4*)&wb[o0*512 + l*4]       = a00;
    *(float4*)&wb[o0*512 + l*4 + 256] = a01;
    *(float4*)&wb[o1*512 + l*4]       = a10;
    *(float4*)&wb[o1*512 + l*4 + 256] = a11;
  }
  __syncthreads();

  // ===== init 3: WCL = WCtmp @ Wl (16x1024) -> wa; WC@bl piggyback =====
  {
    float4 c00={0,0,0,0}, c01=c00, c02=c00, c03=c00;
    float4 c10=c00, c11=c00, c12=c00, c13=c00;
    float wl0=0.f, wl1=0.f;
    for (int m = 0; m < 512; m++){
      float t0 = wb[o0*512 + m], t1 = wb[o1*512 + m];
      float blm = blp[m];
      wl0 += t0*blm; wl1 += t1*blm;
      float4 q0 = *(const float4*)&Wl[m*1024 + l*4];
      float4 q1 = *(const float4*)&Wl[m*1024 + l*4 + 256];
      float4 q2 = *(const float4*)&Wl[m*1024 + l*4 + 512];
      float4 q3 = *(const float4*)&Wl[m*1024 + l*4 + 768];
      FMA4(c00,t0,q0); FMA4(c01,t0,q1); FMA4(c02,t0,q2); FMA4(c03,t0,q3);
      FMA4(c10,t1,q0); FMA4(c11,t1,q1); FMA4(c12,t1,q2); FMA4(c13,t1,q3);
    }
    *(float4*)&wa[o0*1024 + l*4      ] = c00;
    *(float4*)&wa[o0*1024 + l*4 + 256] = c01;
    *(float4*)&wa[o0*1024 + l*4 + 512] = c02;
    *(float4*)&wa[o0*1024 + l*4 + 768] = c03;
    *(float4*)&wa[o1*1024 + l*4      ] = c10;
    *(float4*)&wa[o1*1024 + l*4 + 256] = c11;
    *(float4*)&wa[o1*1024 + l*4 + 512] = c12;
    *(float4*)&wa[o1*1024 + l*4 + 768] = c13;
    if (l == 0){ s_sums[w*2+0] = wl0; s_sums[w*2+1] = wl1; }
  }
  __syncthreads();

  // ===== init 4: per-row bias regs (wave 0); rsWC from resident WCtmp =====
  float biasAreg=0.f, biasBreg=0.f, bE2reg=0.f, rsReg=0.f;
  float bl0=0.f, bl1=0.f, c1=0.f, c2=0.f;
  if (w == 0 && l < 16){
    int r = (l >> 2)*1024 + wid*4 + (l & 3);
    biasAreg = bih1[r] + bhh1[r];
    biasBreg = bih2[r] + bhh2[r];
    float acc = s_sums[(l>>1)*2 + (l&1)];     // WC@bl for this row
    for (int e = 0; e < 128; e++) acc += s_in[l*128 + e] * bmp[e];
    bE2reg = acc;
    float rsum = 0.f;
    for (int m = 0; m < 512; m += 4){
      float4 v = *(float4*)&wb[l*512 + m];    // WCtmp row l (still resident)
      rsum += v.x + v.y + v.z + v.w;
    }
    rsReg = rsum;
  }
  if (w == 0 && l == 0){ bl0 = blp[wid*2]; bl1 = blp[wid*2 + 1]; }
  __syncthreads();     // init4's s_in/wb reads done before overwrite below

  // ===== init 5: zero h1/h2; stage feat(0); LDS weights wb, wy ====
  for (int idx = tid; idx < 2048; idx += 512) s_in[512 + idx] = 0.f;
  if (tid < 256)
    *(float2*)&s_in[tid*2] = *(const float2*)&featp[tid*2];
  for (int o = 0; o < 16; o++){
    int r = (o >> 2)*1024 + wid*4 + (o & 3);
    for (int c = tid; c < 768; c += 512)
      wb[o*768 + c] = Whh2[r*1024 + 256 + c];
  }
  for (int idx = tid; idx < 2048; idx += 512){
    int row = idx >> 10, c = idx & 1023;
    wy[idx] = Wl[(wid*2 + row)*1024 + c];
  }

  // ===== init 6: pinned register weights (88 floats/thread) =====
  float4 wA0[6], wA1[6], wB0[5], wB1[5];
  #pragma unroll
  for (int j = 0; j < 6; j++){
    int c = 256*j + l*4;
    wA0[j] = (c < 512) ? *(const float4*)&Wih1[rA0*640 + c]
                       : *(const float4*)&Whh1[rA0*1024 + c - 512];
    wA1[j] = (c < 512) ? *(const float4*)&Wih1[rA1*640 + c]
                       : *(const float4*)&Whh1[rA1*1024 + c - 512];
  }
  #pragma unroll
  for (int j = 0; j < 5; j++){
    int c = 256*j + l*4;
    wB0[j] = (c < 1024) ? *(const float4*)&Wih2[rA0*1024 + c]
                        : *(const float4*)&Whh2[rA0*1024 + c - 1024];
    wB1[j] = (c < 1024) ? *(const float4*)&Wih2[rA1*1024 + c]
                        : *(const float4*)&Whh2[rA1*1024 + c - 1024];
  }
  #pragma unroll
  for (int j = 0; j < 6; j++){ PIN4(wA0[j]); PIN4(wA1[j]); }
  #pragma unroll
  for (int j = 0; j < 5; j++){ PIN4(wB0[j]); PIN4(wB1[j]); }
  PIN1(biasAreg); PIN1(biasBreg); PIN1(bE2reg); PIN1(rsReg);
  PIN1(bl0); PIN1(bl1);
  __syncthreads();

  // ===== main loop =====
  for (int t = 0; t < T_STEPS; t++){
    const int pprev = (t + 1) & 1;       // parity of step t-1
    const int pcur  = t & 1;             // parity of step t

    // ---- A2: partial gates1 (feat+h1, reg weights). No loop-top sync:
    //      feat(t) staged during B1(t-1); h1(t-1) in LDS from B1(t-1). ----
    float acc0 = 0.f, acc1 = 0.f;
    #pragma unroll
    for (int j = 0; j < 6; j++){
      float4 xv = *(float4*)&s_in[256*j + l*4];
      acc0 += DOT4(wA0[j], xv); acc1 += DOT4(wA1[j], xv);
    }

    // ---- A3: poll h2(t-1) record (single ld16 + sleep pacing, as R11) ----
    if (t > 0){
      const u32x4* p2 = rh2 + pprev*512 + tid;
      u32x4 b;
      for(;;){
        b = ld16(p2);
        if (b.z >= (unsigned)t) break;
        __builtin_amdgcn_s_sleep(1);
      }
      *(float2*)&s_in[1536 + 2*tid] =
          make_float2(__uint_as_float(b.x), __uint_as_float(b.y));
    }
    __syncthreads();

    // ---- A4: wave0: y(t-1) dot + publish ry + out; all: WCL dot + pB ----
    if (t > 0 && w == 0){
      float y0 = 0.f, y1 = 0.f;
      #pragma unroll
      for (int i = 0; i < 4; i++){
        float4 xv = *(float4*)&s_in[1536 + 256*i + l*4];
        float4 w0 = *(float4*)&wy[256*i + l*4];
        float4 w1 = *(float4*)&wy[1024 + 256*i + l*4];
        y0 += DOT4(w0, xv); y1 += DOT4(w1, xv);
      }
      #pragma unroll
      for (int mk = 32; mk; mk >>= 1){
        y0 += __shfl_xor(y0, mk); y1 += __shfl_xor(y1, mk);
      }
      if (l == 0){
        y0 += bl0; y1 += bl1;
        *(float2*)&out[(size_t)(t-1)*512 + wid*2] = make_float2(y0, y1);
        u32x4 rec;
        rec.x = __float_as_uint(y0); rec.y = __float_as_uint(y1);
        rec.z = (unsigned)t; rec.w = 0u;
        st16(ry + pcur*256 + wid, rec);
      }
    }
    #pragma unroll
    for (int k = 0; k < 4; k++){
      float4 xv = *(float4*)&s_in[1536 + 256*k + l*4];
      float4 u0 = *(float4*)&wa[o0*1024 + 256*k + l*4];
      float4 u1 = *(float4*)&wa[o1*1024 + 256*k + l*4];
      acc0 += DOT4(u0, xv); acc1 += DOT4(u1, xv);
    }
    #pragma unroll
    for (int mk = 32; mk; mk >>= 1){
      acc0 += __shfl_xor(acc0, mk); acc1 += __shfl_xor(acc1, mk);
    }
    if (l == 0){ s_part[o0] = acc0; s_part[o1] = acc1; }

    // pB: precompute gates2's h2-dependent half (h2 in s_in[1536,2560))
    float pB0, pB1;
    {
      float4 xv = *(float4*)&s_in[1536 + l*4];
      pB0 = DOT4(wB0[4], xv); pB1 = DOT4(wB1[4], xv);
      #pragma unroll
      for (int k = 0; k < 3; k++){
        float4 x2 = *(float4*)&s_in[1536 + 256 + 256*k + l*4];
        float4 u0 = *(float4*)&wb[o0*768 + 256*k + l*4];
        float4 u1 = *(float4*)&wb[o1*768 + 256*k + l*4];
        pB0 += DOT4(u0, x2); pB1 += DOT4(u1, x2);
      }
    }
    __syncthreads();

    // ---- A5: finalize (wave0): batched lse poll (sleep-paced), publish rh1
    if (w == 0){
      float lse = 0.f;
      if (t > 0){
        const u32x4* pyr = ry + pcur*256 + 4*l;
        u32x4 r0, r1, r2, r3;
        for(;;){
          ld16x4(pyr, r0, r1, r2, r3);
          if (r0.z >= (unsigned)t && r1.z >= (unsigned)t &&
              r2.z >= (unsigned)t && r3.z >= (unsigned)t) break;
          __builtin_amdgcn_s_sleep(1);
        }
        float v0 = __uint_as_float(r0.x), v1 = __uint_as_float(r0.y);
        float v2 = __uint_as_float(r1.x), v3 = __uint_as_float(r1.y);
        float v4 = __uint_as_float(r2.x), v5 = __uint_as_float(r2.y);
        float v6 = __uint_as_float(r3.x), v7 = __uint_as_float(r3.y);
        float m0 = fmaxf(fmaxf(fmaxf(v0,v1), fmaxf(v2,v3)),
                         fmaxf(fmaxf(v4,v5), fmaxf(v6,v7)));
        #pragma unroll
        for (int mk = 32; mk; mk >>= 1) m0 = fmaxf(m0, __shfl_xor(m0, mk));
        float s = expf(v0-m0)+expf(v1-m0)+expf(v2-m0)+expf(v3-m0)
                + expf(v4-m0)+expf(v5-m0)+expf(v6-m0)+expf(v7-m0);
        #pragma unroll
        for (int mk = 32; mk; mk >>= 1) s += __shfl_xor(s, mk);
        lse = m0 + logf(s);
      }
      float hn = 0.f;
      if (l < 16){
        float sum = s_part[l] + biasAreg;
        if (t > 0) sum += bE2reg - rsReg*lse;
        float gi = __shfl(sum, (l & 3));
        float gf = __shfl(sum, 4 + (l & 3));
        float gg = __shfl(sum, 8 + (l & 3));
        float go = __shfl(sum, 12 + (l & 3));
        if (l < 4){
          float cn = sigm(gf)*c1 + sigm(gi)*tanhf(gg);
          c1 = cn;
          hn = sigm(go)*tanhf(cn);
        }
      }
      float g0 = __shfl(hn, 2*(l & 1));
      float g1 = __shfl(hn, 2*(l & 1) + 1);
      if (l < 2){
        u32x4 rec;
        rec.x = __float_as_uint(g0); rec.y = __float_as_uint(g1);
        rec.z = (unsigned)(t + 1); rec.w = 0u;
        st16(rh1 + pcur*512 + wid*2 + l, rec);
      }
    }

    // ---- B1: issue feat(t+1) load; poll rh1 (ld16+sleep); stage both ----
    float2 fv;
    if (tid < 256){
      int tn = (t + 1 < T_STEPS) ? (t + 1) : t;
      fv = *(const float2*)&featp[(size_t)tn*512 + tid*2];
    }
    {
      const u32x4* p1 = rh1 + pcur*512 + tid;
      u32x4 a;
      for(;;){
        a = ld16(p1);
        if (a.z >= (unsigned)(t + 1)) break;
        __builtin_amdgcn_s_sleep(1);
      }
      *(float2*)&s_in[512 + 2*tid] =
          make_float2(__uint_as_float(a.x), __uint_as_float(a.y));
    }
    if (tid < 256) *(float2*)&s_in[tid*2] = fv;
    __syncthreads();

    // ---- B2: gates2 dot: regs j=0..3 on h1 + precomputed pB ----
    float b0 = pB0, b1 = pB1;
    #pragma unroll
    for (int j = 0; j < 4; j++){
      float4 xv = *(float4*)&s_in[512 + 256*j + l*4];
      b0 += DOT4(wB0[j], xv); b1 += DOT4(wB1[j], xv);
    }
    #pragma unroll
    for (int mk = 32; mk; mk >>= 1){
      b0 += __shfl_xor(b0, mk); b1 += __shfl_xor(b1, mk);
    }
    if (l == 0){ s_part[o0] = b0; s_part[o1] = b1; }
    __syncthreads();

    // ---- B3: finalize h2 (wave0), publish rh2 ----
    if (w == 0){
      float hn = 0.f;
      if (l < 16){
        float sum = s_part[l] + biasBreg;
        float gi = __shfl(sum, (l & 3));
        float gf = __shfl(sum, 4 + (l & 3));
        float gg = __shfl(sum, 8 + (l & 3));
        float go = __shfl(sum, 12 + (l & 3));
        if (l < 4){
          float cn = sigm(gf)*c2 + sigm(gi)*tanhf(gg);
          c2 = cn;
          hn = sigm(go)*tanhf(cn);
        }
      }
      float g0 = __shfl(hn, 2*(l & 1));
      float g1 = __shfl(hn, 2*(l & 1) + 1);
      if (l < 2){
        u32x4 rec;
        rec.x = __float_as_uint(g0); rec.y = __float_as_uint(g1);
        rec.z = (unsigned)(t + 1); rec.w = 0u;
        st16(rh2 + pcur*512 + wid*2 + l, rec);
      }
    }
  }

  // ===== tail: y(T-1) from rh2[(T-1)&1] records =====
  {
    const u32x4* p2 = rh2 + ((T_STEPS - 1) & 1)*512 + tid;
    u32x4 b;
    for(;;){
      b = ld16(p2);
      if (b.z >= (unsigned)T_STEPS) break;
      __builtin_amdgcn_s_sleep(1);
    }
    *(float2*)&s_in[1536 + 2*tid] =
        make_float2(__uint_as_float(b.x), __uint_as_float(b.y));
  }
  __syncthreads();
  if (w == 0){
    float y0 = 0.f, y1 = 0.f;
    #pragma unroll
    for (int i = 0; i < 4; i++){
      float4 xv = *(float4*)&s_in[1536 + 256*i + l*4];
      float4 w0 = *(float4*)&wy[256*i + l*4];
      float4 w1 = *(float4*)&wy[1024 + 256*i + l*4];
      y0 += DOT4(w0, xv); y1 += DOT4(w1, xv);
    }
    #pragma unroll
    for (int mk = 32; mk; mk >>= 1){
      y0 += __shfl_xor(y0, mk); y1 += __shfl_xor(y1, mk);
    }
    if (l == 0)
      *(float2*)&out[(size_t)(T_STEPS-1)*512 + wid*2] =
          make_float2(y0 + bl0, y1 + bl1);
  }
}

// ---------------------------------------------------------------------------
extern "C" void kernel_launch(void* const* d_in, const int* in_sizes, int n_in,
                              void* d_out, int out_size, void* d_ws, size_t ws_size,
                              hipStream_t stream)
{
  const float* x    = (const float*)d_in[0];
  const float* Ws   = (const float*)d_in[1];
  const float* bs   = (const float*)d_in[2];
  const float* Wih1 = (const float*)d_in[3];
  const float* Whh1 = (const float*)d_in[4];
  const float* bih1 = (const float*)d_in[5];
  const float* bhh1 = (const float*)d_in[6];
  const float* Wih2 = (const float*)d_in[7];
  const float* Whh2 = (const float*)d_in[8];
  const float* bih2 = (const float*)d_in[9];
  const float* bhh2 = (const float*)d_in[10];
  const float* Wl   = (const float*)d_in[11];
  const float* bl   = (const float*)d_in[12];
  const float* Wm   = (const float*)d_in[13];
  const float* bm   = (const float*)d_in[14];
  char* wsb  = (char*)d_ws;
  float* out = (float*)d_out;

  // zero records (seq=0 < any need) -- fresh each call / graph replay
  hipMemsetAsync(wsb, 0, WS_ZERO_BYTES, stream);

  feat_kernel<<<256, 512, 0, stream>>>(x, Ws, bs, (float*)(wsb + WS_FEAT));
  lstm_persist<<<NWG, 512, SMEM_BYTES, stream>>>(
      Wih1, Whh1, Wih2, Whh2, Wl, Wm,
      bih1, bhh1, bih2, bhh2, bl, bm, wsb, out);
  ls_kernel<<<T_STEPS, 64, 0, stream>>>(out);
}

// Round 15
// 28127.811 us; speedup vs baseline: 2.3480x; 1.0539x over previous
//
#include <hip/hip_runtime.h>
#include <math.h>

// ---------------------------------------------------------------------------
// LSTM_FEAT_2: T=4096 sequential 2-layer LSTM + log-softmax feedback.
// R15 = R14 + loop-bottom __syncthreads (after B3).
// R14's regression (29.6ms vs R11's 25.1) was traced to deleting the
// loop-top sync: waves 1-7 spin-polled rh2 while their own wg's wave0 was
// still computing/publishing B3 on the same CU -> poller pressure throttled
// producers chip-wide (FETCH 590->787MB). The loop-bottom sync restores
// producer protection (publish issued before any wave re-enters a poll)
// while keeping feat(t+1) staged under B1's rh1 gap (edit #2).
//
// Math (unchanged, verified R7-R14):
//   feat_t = Ws@x_t + bs                       (startup kernel)
//   gates1 = [Wih1s|Whh1]@[feat;h1] + WCL@h2 + biasA [+ biasE2 - rsWC*lse]
//     WCL=(Wih1e@Wm)@Wl, biasE2=Wih1e@bm+WC@bl, rsWC=rowsum(WC)
//   gates2 = [Wih2|Whh2]@[h1;h2] + biasB
//   y_t    = Wl@h2_t + bl -> d_out ; post-pass: out = log_softmax(out)
// ---------------------------------------------------------------------------

#define T_STEPS 4096
#define NWG 256

typedef unsigned u32x4 __attribute__((ext_vector_type(4)));

// ws layout (bytes)
#define WS_RH1   0            // u32x4[2][512]: h1 records {h,h,seq,0} (16KB)
#define WS_RH2   16384        // u32x4[2][512]: h2 records (16KB)
#define WS_RY    32768        // u32x4[2][256]: y records {y0,y1,seq,0} (8KB)
#define WS_ZERO_BYTES 40960
#define WS_FEAT  40960        // float[4096][512] -> end ~8.4MB

// dynamic LDS partition (floats)
#define OFF_WA 2560           // s_in[2560] | wa[16][1024] | wb[16][768] | wy[2][1024]
#define OFF_WB 18944
#define OFF_WY 31232
#define SMEM_FLOATS 33280
#define SMEM_BYTES  (SMEM_FLOATS*4)

#define PIN4(v) asm volatile("" : "+v"((v).x), "+v"((v).y), "+v"((v).z), "+v"((v).w))
#define PIN1(v) asm volatile("" : "+v"(v))
#define FMA4(acc,s,v4) {(acc).x += (s)*(v4).x; (acc).y += (s)*(v4).y; (acc).z += (s)*(v4).z; (acc).w += (s)*(v4).w;}
#define DOT4(a,b) ((a).x*(b).x + (a).y*(b).y + (a).z*(b).z + (a).w*(b).w)

// coherent 16B transactional load/store (bypass L1/L2 -> LLC)
__device__ __forceinline__ u32x4 ld16(const u32x4* p){
  u32x4 r;
  asm volatile("global_load_dwordx4 %0, %1, off sc0 sc1\n\ts_waitcnt vmcnt(0)"
               : "=v"(r) : "v"(p) : "memory");
  return r;
}
// 4 contiguous records, ONE waitcnt (offset immediates)
__device__ __forceinline__ void ld16x4(const u32x4* p, u32x4& r0, u32x4& r1,
                                       u32x4& r2, u32x4& r3){
  asm volatile("global_load_dwordx4 %0, %4, off sc0 sc1\n\t"
               "global_load_dwordx4 %1, %4, off offset:16 sc0 sc1\n\t"
               "global_load_dwordx4 %2, %4, off offset:32 sc0 sc1\n\t"
               "global_load_dwordx4 %3, %4, off offset:48 sc0 sc1\n\t"
               "s_waitcnt vmcnt(0)"
               : "=&v"(r0), "=&v"(r1), "=&v"(r2), "=&v"(r3)
               : "v"(p) : "memory");
}
__device__ __forceinline__ void st16(u32x4* p, u32x4 v){
  asm volatile("global_store_dwordx4 %0, %1, off sc0 sc1"
               :: "v"(p), "v"(v) : "memory");
}
__device__ __forceinline__ float sigm(float x){ return 1.0f/(1.0f+expf(-x)); }

// ---------------------------------------------------------------------------
// startup: feat[t][k] = Ws[k]·x[t] + bs[k]
__global__ __launch_bounds__(512) void feat_kernel(
    const float* __restrict__ x, const float* __restrict__ Ws,
    const float* __restrict__ bs, float* __restrict__ feat)
{
  __shared__ float s_x[16][360];
  __shared__ float s_w[512][20];
  const int bid = blockIdx.x, tid = threadIdx.x;
  const int t0 = bid * 16;
  for (int tt = 0; tt < 16; tt++)
    if (tid < 360) s_x[tt][tid] = x[(t0+tt)*360 + tid];
  float acc[16];
  #pragma unroll
  for (int i = 0; i < 16; i++) acc[i] = 0.f;
  for (int d0 = 0; d0 < 360; d0 += 16){
    const int dn = (360 - d0 < 16) ? (360 - d0) : 16;
    __syncthreads();
    if (dn == 16){
      #pragma unroll
      for (int c4 = 0; c4 < 4; c4++)
        *(float4*)&s_w[tid][c4*4] = *(const float4*)&Ws[tid*360 + d0 + c4*4];
    } else {
      for (int c = 0; c < dn; c++) s_w[tid][c] = Ws[tid*360 + d0 + c];
    }
    __syncthreads();
    for (int c = 0; c < dn; c++){
      float wv = s_w[tid][c];
      #pragma unroll
      for (int tt = 0; tt < 16; tt++) acc[tt] += wv * s_x[tt][d0 + c];
    }
  }
  for (int tt = 0; tt < 16; tt++)
    feat[(t0+tt)*512 + tid] = acc[tt] + bs[tid];
}

// ---------------------------------------------------------------------------
// post-pass: out[t] = out[t] - logsumexp(out[t])  (in place)
__global__ __launch_bounds__(64) void ls_kernel(float* __restrict__ out)
{
  const int t = blockIdx.x, l = threadIdx.x;
  float v[8];
  #pragma unroll
  for (int i = 0; i < 8; i++) v[i] = out[t*512 + l*8 + i];
  float m0 = v[0];
  #pragma unroll
  for (int i = 1; i < 8; i++) m0 = fmaxf(m0, v[i]);
  #pragma unroll
  for (int mk = 32; mk; mk >>= 1) m0 = fmaxf(m0, __shfl_xor(m0, mk));
  float s = 0.f;
  #pragma unroll
  for (int i = 0; i < 8; i++) s += expf(v[i] - m0);
  #pragma unroll
  for (int mk = 32; mk; mk >>= 1) s += __shfl_xor(s, mk);
  float lse = m0 + logf(s);
  #pragma unroll
  for (int i = 0; i < 8; i++) out[t*512 + l*8 + i] = v[i] - lse;
}

// ---------------------------------------------------------------------------
// persistent kernel: 256 wgs x 512 thr (8 waves), 1 wg/CU via 133KB LDS.
// Wave w owns gate rows {2w,2w+1}; lane l owns f4 col-chunks (bank-clean).
// s_in layout (persistent): feat[0,512) | h1[512,1536) | h2[1536,2560).
__global__ __launch_bounds__(512, 1) void lstm_persist(
    const float* __restrict__ Wih1, const float* __restrict__ Whh1,
    const float* __restrict__ Wih2, const float* __restrict__ Whh2,
    const float* __restrict__ Wl,   const float* __restrict__ Wm,
    const float* __restrict__ bih1, const float* __restrict__ bhh1,
    const float* __restrict__ bih2, const float* __restrict__ bhh2,
    const float* __restrict__ blp,  const float* __restrict__ bmp,
    char* __restrict__ wsb, float* __restrict__ out)
{
  extern __shared__ float smem[];
  float* s_in = smem;               // feat | h1 | h2 (persistent regions)
  float* wa   = smem + OFF_WA;      // [16][1024] = WCL rows
  float* wb   = smem + OFF_WB;      // [16][768]  = Whh2 cols 256..1023 (init: WCtmp)
  float* wy   = smem + OFF_WY;      // [2][1024]  = Wl rows wid*2, wid*2+1
  __shared__ float s_part[16];
  __shared__ float s_sums[32];

  u32x4* rh1 = (u32x4*)(wsb + WS_RH1);   // [2][512]
  u32x4* rh2 = (u32x4*)(wsb + WS_RH2);   // [2][512]
  u32x4* ry  = (u32x4*)(wsb + WS_RY);    // [2][256]
  const float* featp = (const float*)(wsb + WS_FEAT);

  const int wid = blockIdx.x, tid = threadIdx.x;
  const int w = tid >> 6, l = tid & 63;
  const int o0 = 2*w, o1 = 2*w + 1;
  const int rA0 = (o0 >> 2)*1024 + wid*4 + (o0 & 3);
  const int rA1 = (o1 >> 2)*1024 + wid*4 + (o1 & 3);

  // ===== init 1: stage this wg's 16 Wih1e rows (16x128) into s_in =====
  for (int idx = tid; idx < 2048; idx += 512){
    int o = idx >> 7, e = idx & 127;
    int r = (o >> 2)*1024 + wid*4 + (o & 3);
    s_in[idx] = Wih1[r*640 + 512 + e];
  }
  __syncthreads();

  // ===== init 2: WCtmp = Wih1e @ Wm  (16x512) -> wb area =====
  {
    float4 a00 = {0,0,0,0}, a01 = a00, a10 = a00, a11 = a00;
    for (int e = 0; e < 128; e++){
      float w0e = s_in[o0*128 + e], w1e = s_in[o1*128 + e];
      float4 m0 = *(const float4*)&Wm[e*512 + l*4];
      float4 m1 = *(const float4*)&Wm[e*512 + l*4 + 256];
      FMA4(a00, w0e, m0); FMA4(a01, w0e, m1);
      FMA4(a10, w1e, m0); FMA4(a11, w1e, m1);
    }
    *(float4*)&wb[o0*512 + l*4]       = a00;
    *(float4*)&wb[o0*512 + l*4 + 256] = a01;
    *(float4*)&wb[o1*512 + l*4]       = a10;
    *(float4*)&wb[o1*512 + l*4 + 256] = a11;
  }
  __syncthreads();

  // ===== init 3: WCL = WCtmp @ Wl (16x1024) -> wa; WC@bl piggyback =====
  {
    float4 c00={0,0,0,0}, c01=c00, c02=c00, c03=c00;
    float4 c10=c00, c11=c00, c12=c00, c13=c00;
    float wl0=0.f, wl1=0.f;
    for (int m = 0; m < 512; m++){
      float t0 = wb[o0*512 + m], t1 = wb[o1*512 + m];
      float blm = blp[m];
      wl0 += t0*blm; wl1 += t1*blm;
      float4 q0 = *(const float4*)&Wl[m*1024 + l*4];
      float4 q1 = *(const float4*)&Wl[m*1024 + l*4 + 256];
      float4 q2 = *(const float4*)&Wl[m*1024 + l*4 + 512];
      float4 q3 = *(const float4*)&Wl[m*1024 + l*4 + 768];
      FMA4(c00,t0,q0); FMA4(c01,t0,q1); FMA4(c02,t0,q2); FMA4(c03,t0,q3);
      FMA4(c10,t1,q0); FMA4(c11,t1,q1); FMA4(c12,t1,q2); FMA4(c13,t1,q3);
    }
    *(float4*)&wa[o0*1024 + l*4      ] = c00;
    *(float4*)&wa[o0*1024 + l*4 + 256] = c01;
    *(float4*)&wa[o0*1024 + l*4 + 512] = c02;
    *(float4*)&wa[o0*1024 + l*4 + 768] = c03;
    *(float4*)&wa[o1*1024 + l*4      ] = c10;
    *(float4*)&wa[o1*1024 + l*4 + 256] = c11;
    *(float4*)&wa[o1*1024 + l*4 + 512] = c12;
    *(float4*)&wa[o1*1024 + l*4 + 768] = c13;
    if (l == 0){ s_sums[w*2+0] = wl0; s_sums[w*2+1] = wl1; }
  }
  __syncthreads();

  // ===== init 4: per-row bias regs (wave 0); rsWC from resident WCtmp =====
  float biasAreg=0.f, biasBreg=0.f, bE2reg=0.f, rsReg=0.f;
  float bl0=0.f, bl1=0.f, c1=0.f, c2=0.f;
  if (w == 0 && l < 16){
    int r = (l >> 2)*1024 + wid*4 + (l & 3);
    biasAreg = bih1[r] + bhh1[r];
    biasBreg = bih2[r] + bhh2[r];
    float acc = s_sums[(l>>1)*2 + (l&1)];     // WC@bl for this row
    for (int e = 0; e < 128; e++) acc += s_in[l*128 + e] * bmp[e];
    bE2reg = acc;
    float rsum = 0.f;
    for (int m = 0; m < 512; m += 4){
      float4 v = *(float4*)&wb[l*512 + m];    // WCtmp row l (still resident)
      rsum += v.x + v.y + v.z + v.w;
    }
    rsReg = rsum;
  }
  if (w == 0 && l == 0){ bl0 = blp[wid*2]; bl1 = blp[wid*2 + 1]; }
  __syncthreads();     // init4's s_in/wb reads done before overwrite below

  // ===== init 5: zero h1/h2; stage feat(0); LDS weights wb, wy ====
  for (int idx = tid; idx < 2048; idx += 512) s_in[512 + idx] = 0.f;
  if (tid < 256)
    *(float2*)&s_in[tid*2] = *(const float2*)&featp[tid*2];
  for (int o = 0; o < 16; o++){
    int r = (o >> 2)*1024 + wid*4 + (o & 3);
    for (int c = tid; c < 768; c += 512)
      wb[o*768 + c] = Whh2[r*1024 + 256 + c];
  }
  for (int idx = tid; idx < 2048; idx += 512){
    int row = idx >> 10, c = idx & 1023;
    wy[idx] = Wl[(wid*2 + row)*1024 + c];
  }

  // ===== init 6: pinned register weights (88 floats/thread) =====
  float4 wA0[6], wA1[6], wB0[5], wB1[5];
  #pragma unroll
  for (int j = 0; j < 6; j++){
    int c = 256*j + l*4;
    wA0[j] = (c < 512) ? *(const float4*)&Wih1[rA0*640 + c]
                       : *(const float4*)&Whh1[rA0*1024 + c - 512];
    wA1[j] = (c < 512) ? *(const float4*)&Wih1[rA1*640 + c]
                       : *(const float4*)&Whh1[rA1*1024 + c - 512];
  }
  #pragma unroll
  for (int j = 0; j < 5; j++){
    int c = 256*j + l*4;
    wB0[j] = (c < 1024) ? *(const float4*)&Wih2[rA0*1024 + c]
                        : *(const float4*)&Whh2[rA0*1024 + c - 1024];
    wB1[j] = (c < 1024) ? *(const float4*)&Wih2[rA1*1024 + c]
                        : *(const float4*)&Whh2[rA1*1024 + c - 1024];
  }
  #pragma unroll
  for (int j = 0; j < 6; j++){ PIN4(wA0[j]); PIN4(wA1[j]); }
  #pragma unroll
  for (int j = 0; j < 5; j++){ PIN4(wB0[j]); PIN4(wB1[j]); }
  PIN1(biasAreg); PIN1(biasBreg); PIN1(bE2reg); PIN1(rsReg);
  PIN1(bl0); PIN1(bl1);
  __syncthreads();

  // ===== main loop =====
  for (int t = 0; t < T_STEPS; t++){
    const int pprev = (t + 1) & 1;       // parity of step t-1
    const int pcur  = t & 1;             // parity of step t

    // ---- A2: partial gates1 (feat+h1, reg weights). Loop-bottom sync
    //      guarantees feat(t)/h1(t-1) staged and rh2 publish issued. ----
    float acc0 = 0.f, acc1 = 0.f;
    #pragma unroll
    for (int j = 0; j < 6; j++){
      float4 xv = *(float4*)&s_in[256*j + l*4];
      acc0 += DOT4(wA0[j], xv); acc1 += DOT4(wA1[j], xv);
    }

    // ---- A3: poll h2(t-1) record (single ld16 + sleep pacing) ----
    if (t > 0){
      const u32x4* p2 = rh2 + pprev*512 + tid;
      u32x4 b;
      for(;;){
        b = ld16(p2);
        if (b.z >= (unsigned)t) break;
        __builtin_amdgcn_s_sleep(1);
      }
      *(float2*)&s_in[1536 + 2*tid] =
          make_float2(__uint_as_float(b.x), __uint_as_float(b.y));
    }
    __syncthreads();

    // ---- A4: wave0: y(t-1) dot + publish ry + out; all: WCL dot + pB ----
    if (t > 0 && w == 0){
      float y0 = 0.f, y1 = 0.f;
      #pragma unroll
      for (int i = 0; i < 4; i++){
        float4 xv = *(float4*)&s_in[1536 + 256*i + l*4];
        float4 w0 = *(float4*)&wy[256*i + l*4];
        float4 w1 = *(float4*)&wy[1024 + 256*i + l*4];
        y0 += DOT4(w0, xv); y1 += DOT4(w1, xv);
      }
      #pragma unroll
      for (int mk = 32; mk; mk >>= 1){
        y0 += __shfl_xor(y0, mk); y1 += __shfl_xor(y1, mk);
      }
      if (l == 0){
        y0 += bl0; y1 += bl1;
        *(float2*)&out[(size_t)(t-1)*512 + wid*2] = make_float2(y0, y1);
        u32x4 rec;
        rec.x = __float_as_uint(y0); rec.y = __float_as_uint(y1);
        rec.z = (unsigned)t; rec.w = 0u;
        st16(ry + pcur*256 + wid, rec);
      }
    }
    #pragma unroll
    for (int k = 0; k < 4; k++){
      float4 xv = *(float4*)&s_in[1536 + 256*k + l*4];
      float4 u0 = *(float4*)&wa[o0*1024 + 256*k + l*4];
      float4 u1 = *(float4*)&wa[o1*1024 + 256*k + l*4];
      acc0 += DOT4(u0, xv); acc1 += DOT4(u1, xv);
    }
    #pragma unroll
    for (int mk = 32; mk; mk >>= 1){
      acc0 += __shfl_xor(acc0, mk); acc1 += __shfl_xor(acc1, mk);
    }
    if (l == 0){ s_part[o0] = acc0; s_part[o1] = acc1; }

    // pB: precompute gates2's h2-dependent half (h2 in s_in[1536,2560))
    float pB0, pB1;
    {
      float4 xv = *(float4*)&s_in[1536 + l*4];
      pB0 = DOT4(wB0[4], xv); pB1 = DOT4(wB1[4], xv);
      #pragma unroll
      for (int k = 0; k < 3; k++){
        float4 x2 = *(float4*)&s_in[1536 + 256 + 256*k + l*4];
        float4 u0 = *(float4*)&wb[o0*768 + 256*k + l*4];
        float4 u1 = *(float4*)&wb[o1*768 + 256*k + l*4];
        pB0 += DOT4(u0, x2); pB1 += DOT4(u1, x2);
      }
    }
    __syncthreads();

    // ---- A5: finalize (wave0): batched lse poll (sleep-paced), publish rh1
    if (w == 0){
      float lse = 0.f;
      if (t > 0){
        const u32x4* pyr = ry + pcur*256 + 4*l;
        u32x4 r0, r1, r2, r3;
        for(;;){
          ld16x4(pyr, r0, r1, r2, r3);
          if (r0.z >= (unsigned)t && r1.z >= (unsigned)t &&
              r2.z >= (unsigned)t && r3.z >= (unsigned)t) break;
          __builtin_amdgcn_s_sleep(1);
        }
        float v0 = __uint_as_float(r0.x), v1 = __uint_as_float(r0.y);
        float v2 = __uint_as_float(r1.x), v3 = __uint_as_float(r1.y);
        float v4 = __uint_as_float(r2.x), v5 = __uint_as_float(r2.y);
        float v6 = __uint_as_float(r3.x), v7 = __uint_as_float(r3.y);
        float m0 = fmaxf(fmaxf(fmaxf(v0,v1), fmaxf(v2,v3)),
                         fmaxf(fmaxf(v4,v5), fmaxf(v6,v7)));
        #pragma unroll
        for (int mk = 32; mk; mk >>= 1) m0 = fmaxf(m0, __shfl_xor(m0, mk));
        float s = expf(v0-m0)+expf(v1-m0)+expf(v2-m0)+expf(v3-m0)
                + expf(v4-m0)+expf(v5-m0)+expf(v6-m0)+expf(v7-m0);
        #pragma unroll
        for (int mk = 32; mk; mk >>= 1) s += __shfl_xor(s, mk);
        lse = m0 + logf(s);
      }
      float hn = 0.f;
      if (l < 16){
        float sum = s_part[l] + biasAreg;
        if (t > 0) sum += bE2reg - rsReg*lse;
        float gi = __shfl(sum, (l & 3));
        float gf = __shfl(sum, 4 + (l & 3));
        float gg = __shfl(sum, 8 + (l & 3));
        float go = __shfl(sum, 12 + (l & 3));
        if (l < 4){
          float cn = sigm(gf)*c1 + sigm(gi)*tanhf(gg);
          c1 = cn;
          hn = sigm(go)*tanhf(cn);
        }
      }
      float g0 = __shfl(hn, 2*(l & 1));
      float g1 = __shfl(hn, 2*(l & 1) + 1);
      if (l < 2){
        u32x4 rec;
        rec.x = __float_as_uint(g0); rec.y = __float_as_uint(g1);
        rec.z = (unsigned)(t + 1); rec.w = 0u;
        st16(rh1 + pcur*512 + wid*2 + l, rec);
      }
    }

    // ---- B1: issue feat(t+1) load; poll rh1 (ld16+sleep); stage both ----
    float2 fv;
    if (tid < 256){
      int tn = (t + 1 < T_STEPS) ? (t + 1) : t;
      fv = *(const float2*)&featp[(size_t)tn*512 + tid*2];
    }
    {
      const u32x4* p1 = rh1 + pcur*512 + tid;
      u32x4 a;
      for(;;){
        a = ld16(p1);
        if (a.z >= (unsigned)(t + 1)) break;
        __builtin_amdgcn_s_sleep(1);
      }
      *(float2*)&s_in[512 + 2*tid] =
          make_float2(__uint_as_float(a.x), __uint_as_float(a.y));
    }
    if (tid < 256) *(float2*)&s_in[tid*2] = fv;
    __syncthreads();

    // ---- B2: gates2 dot: regs j=0..3 on h1 + precomputed pB ----
    float b0 = pB0, b1 = pB1;
    #pragma unroll
    for (int j = 0; j < 4; j++){
      float4 xv = *(float4*)&s_in[512 + 256*j + l*4];
      b0 += DOT4(wB0[j], xv); b1 += DOT4(wB1[j], xv);
    }
    #pragma unroll
    for (int mk = 32; mk; mk >>= 1){
      b0 += __shfl_xor(b0, mk); b1 += __shfl_xor(b1, mk);
    }
    if (l == 0){ s_part[o0] = b0; s_part[o1] = b1; }
    __syncthreads();

    // ---- B3: finalize h2 (wave0), publish rh2 ----
    if (w == 0){
      float hn = 0.f;
      if (l < 16){
        float sum = s_part[l] + biasBreg;
        float gi = __shfl(sum, (l & 3));
        float gf = __shfl(sum, 4 + (l & 3));
        float gg = __shfl(sum, 8 + (l & 3));
        float go = __shfl(sum, 12 + (l & 3));
        if (l < 4){
          float cn = sigm(gf)*c2 + sigm(gi)*tanhf(gg);
          c2 = cn;
          hn = sigm(go)*tanhf(cn);
        }
      }
      float g0 = __shfl(hn, 2*(l & 1));
      float g1 = __shfl(hn, 2*(l & 1) + 1);
      if (l < 2){
        u32x4 rec;
        rec.x = __float_as_uint(g0); rec.y = __float_as_uint(g1);
        rec.z = (unsigned)(t + 1); rec.w = 0u;
        st16(rh2 + pcur*512 + wid*2 + l, rec);
      }
    }
    // producer protection: rh2 store issued before any wave re-enters a poll
    __syncthreads();
  }

  // ===== tail: y(T-1) from rh2[(T-1)&1] records =====
  {
    const u32x4* p2 = rh2 + ((T_STEPS - 1) & 1)*512 + tid;
    u32x4 b;
    for(;;){
      b = ld16(p2);
      if (b.z >= (unsigned)T_STEPS) break;
      __builtin_amdgcn_s_sleep(1);
    }
    *(float2*)&s_in[1536 + 2*tid] =
        make_float2(__uint_as_float(b.x), __uint_as_float(b.y));
  }
  __syncthreads();
  if (w == 0){
    float y0 = 0.f, y1 = 0.f;
    #pragma unroll
    for (int i = 0; i < 4; i++){
      float4 xv = *(float4*)&s_in[1536 + 256*i + l*4];
      float4 w0 = *(float4*)&wy[256*i + l*4];
      float4 w1 = *(float4*)&wy[1024 + 256*i + l*4];
      y0 += DOT4(w0, xv); y1 += DOT4(w1, xv);
    }
    #pragma unroll
    for (int mk = 32; mk; mk >>= 1){
      y0 += __shfl_xor(y0, mk); y1 += __shfl_xor(y1, mk);
    }
    if (l == 0)
      *(float2*)&out[(size_t)(T_STEPS-1)*512 + wid*2] =
          make_float2(y0 + bl0, y1 + bl1);
  }
}

// ---------------------------------------------------------------------------
extern "C" void kernel_launch(void* const* d_in, const int* in_sizes, int n_in,
                              void* d_out, int out_size, void* d_ws, size_t ws_size,
                              hipStream_t stream)
{
  const float* x    = (const float*)d_in[0];
  const float* Ws   = (const float*)d_in[1];
  const float* bs   = (const float*)d_in[2];
  const float* Wih1 = (const float*)d_in[3];
  const float* Whh1 = (const float*)d_in[4];
  const float* bih1 = (const float*)d_in[5];
  const float* bhh1 = (const float*)d_in[6];
  const float* Wih2 = (const float*)d_in[7];
  const float* Whh2 = (const float*)d_in[8];
  const float* bih2 = (const float*)d_in[9];
  const float* bhh2 = (const float*)d_in[10];
  const float* Wl   = (const float*)d_in[11];
  const float* bl   = (const float*)d_in[12];
  const float* Wm   = (const float*)d_in[13];
  const float* bm   = (const float*)d_in[14];
  char* wsb  = (char*)d_ws;
  float* out = (float*)d_out;

  // zero records (seq=0 < any need) -- fresh each call / graph replay
  hipMemsetAsync(wsb, 0, WS_ZERO_BYTES, stream);

  feat_kernel<<<256, 512, 0, stream>>>(x, Ws, bs, (float*)(wsb + WS_FEAT));
  lstm_persist<<<NWG, 512, SMEM_BYTES, stream>>>(
      Wih1, Whh1, Wih2, Whh2, Wl, Wm,
      bih1, bhh1, bih2, bhh2, bl, bm, wsb, out);
  ls_kernel<<<T_STEPS, 64, 0, stream>>>(out);
}

// Round 16
// 25101.918 us; speedup vs baseline: 2.6310x; 1.1205x over previous
//
#include <hip/hip_runtime.h>
#include <math.h>

// ---------------------------------------------------------------------------
// LSTM_FEAT_2: T=4096 sequential 2-layer LSTM + log-softmax feedback.
// R16 = EXACT RESTORE of R11 (25.1ms champion).
// Ablation record: R12 (deferred-lse base-gate records) 66ms REFUTED
// (4x record volume + 64B fanout polls -> contention storm); R13 (sleepless
// 2-deep polls) 31.3ms REFUTED (poll rate throttles producers); R14 (feat
// staged under rh1 gap, no loop-top sync) 29.6ms REFUTED (waves 1-7 spin
// during own-CU producer's B3); R15 (R14 + loop-bottom sync) 28.1ms STILL
// WORSE (lost A1's publish->poll spacing; feat load in poll window).
// Invariant learned: any edit that raises poll pressure or shrinks
// publish->poll spacing loses more to contention than it saves in latency.
// R11 structure: fused data+seq 16B records (poll == data load), persistent
// LDS feat|h1|h2 (A never polls rh1), partial gates1 before rh2 poll,
// batched lse poll, sleep-paced single-ld16 polls, loop-top feat stage.
//
// Math (verified R7-R15):
//   feat_t = Ws@x_t + bs                       (startup kernel)
//   gates1 = [Wih1s|Whh1]@[feat;h1] + WCL@h2 + biasA [+ biasE2 - rsWC*lse]
//     WCL=(Wih1e@Wm)@Wl, biasE2=Wih1e@bm+WC@bl, rsWC=rowsum(WC)
//   gates2 = [Wih2|Whh2]@[h1;h2] + biasB
//   y_t    = Wl@h2_t + bl -> d_out ; post-pass: out = log_softmax(out)
// ---------------------------------------------------------------------------

#define T_STEPS 4096
#define NWG 256

typedef unsigned u32x4 __attribute__((ext_vector_type(4)));

// ws layout (bytes)
#define WS_RH1   0            // u32x4[2][512]: h1 records {h,h,seq,0} (16KB)
#define WS_RH2   16384        // u32x4[2][512]: h2 records (16KB)
#define WS_RY    32768        // u32x4[2][256]: y  records {y0,y1,seq,0} (8KB)
#define WS_ZERO_BYTES 40960
#define WS_FEAT  40960        // float[4096][512] -> end ~8.4MB

// dynamic LDS partition (floats)
#define OFF_WA 2560           // s_in[2560] | wa[16][1024] | wb[16][768] | wy[2][1024]
#define OFF_WB 18944
#define OFF_WY 31232
#define SMEM_FLOATS 33280
#define SMEM_BYTES  (SMEM_FLOATS*4)

#define PIN4(v) asm volatile("" : "+v"((v).x), "+v"((v).y), "+v"((v).z), "+v"((v).w))
#define PIN1(v) asm volatile("" : "+v"(v))
#define FMA4(acc,s,v4) {(acc).x += (s)*(v4).x; (acc).y += (s)*(v4).y; (acc).z += (s)*(v4).z; (acc).w += (s)*(v4).w;}
#define DOT4(a,b) ((a).x*(b).x + (a).y*(b).y + (a).z*(b).z + (a).w*(b).w)

// coherent 16B transactional load/store (bypass L1/L2 -> LLC)
__device__ __forceinline__ u32x4 ld16(const u32x4* p){
  u32x4 r;
  asm volatile("global_load_dwordx4 %0, %1, off sc0 sc1\n\ts_waitcnt vmcnt(0)"
               : "=v"(r) : "v"(p) : "memory");
  return r;
}
// 4 contiguous records, ONE waitcnt (offset immediates)
__device__ __forceinline__ void ld16x4(const u32x4* p, u32x4& r0, u32x4& r1,
                                       u32x4& r2, u32x4& r3){
  asm volatile("global_load_dwordx4 %0, %4, off sc0 sc1\n\t"
               "global_load_dwordx4 %1, %4, off offset:16 sc0 sc1\n\t"
               "global_load_dwordx4 %2, %4, off offset:32 sc0 sc1\n\t"
               "global_load_dwordx4 %3, %4, off offset:48 sc0 sc1\n\t"
               "s_waitcnt vmcnt(0)"
               : "=&v"(r0), "=&v"(r1), "=&v"(r2), "=&v"(r3)
               : "v"(p) : "memory");
}
__device__ __forceinline__ void st16(u32x4* p, u32x4 v){
  asm volatile("global_store_dwordx4 %0, %1, off sc0 sc1"
               :: "v"(p), "v"(v) : "memory");
}
__device__ __forceinline__ float sigm(float x){ return 1.0f/(1.0f+expf(-x)); }

// ---------------------------------------------------------------------------
// startup: feat[t][k] = Ws[k]·x[t] + bs[k]
__global__ __launch_bounds__(512) void feat_kernel(
    const float* __restrict__ x, const float* __restrict__ Ws,
    const float* __restrict__ bs, float* __restrict__ feat)
{
  __shared__ float s_x[16][360];
  __shared__ float s_w[512][20];
  const int bid = blockIdx.x, tid = threadIdx.x;
  const int t0 = bid * 16;
  for (int tt = 0; tt < 16; tt++)
    if (tid < 360) s_x[tt][tid] = x[(t0+tt)*360 + tid];
  float acc[16];
  #pragma unroll
  for (int i = 0; i < 16; i++) acc[i] = 0.f;
  for (int d0 = 0; d0 < 360; d0 += 16){
    const int dn = (360 - d0 < 16) ? (360 - d0) : 16;
    __syncthreads();
    if (dn == 16){
      #pragma unroll
      for (int c4 = 0; c4 < 4; c4++)
        *(float4*)&s_w[tid][c4*4] = *(const float4*)&Ws[tid*360 + d0 + c4*4];
    } else {
      for (int c = 0; c < dn; c++) s_w[tid][c] = Ws[tid*360 + d0 + c];
    }
    __syncthreads();
    for (int c = 0; c < dn; c++){
      float wv = s_w[tid][c];
      #pragma unroll
      for (int tt = 0; tt < 16; tt++) acc[tt] += wv * s_x[tt][d0 + c];
    }
  }
  for (int tt = 0; tt < 16; tt++)
    feat[(t0+tt)*512 + tid] = acc[tt] + bs[tid];
}

// ---------------------------------------------------------------------------
// post-pass: out[t] = out[t] - logsumexp(out[t])  (in place)
__global__ __launch_bounds__(64) void ls_kernel(float* __restrict__ out)
{
  const int t = blockIdx.x, l = threadIdx.x;
  float v[8];
  #pragma unroll
  for (int i = 0; i < 8; i++) v[i] = out[t*512 + l*8 + i];
  float m0 = v[0];
  #pragma unroll
  for (int i = 1; i < 8; i++) m0 = fmaxf(m0, v[i]);
  #pragma unroll
  for (int mk = 32; mk; mk >>= 1) m0 = fmaxf(m0, __shfl_xor(m0, mk));
  float s = 0.f;
  #pragma unroll
  for (int i = 0; i < 8; i++) s += expf(v[i] - m0);
  #pragma unroll
  for (int mk = 32; mk; mk >>= 1) s += __shfl_xor(s, mk);
  float lse = m0 + logf(s);
  #pragma unroll
  for (int i = 0; i < 8; i++) out[t*512 + l*8 + i] = v[i] - lse;
}

// ---------------------------------------------------------------------------
// persistent kernel: 256 wgs x 512 thr (8 waves), 1 wg/CU via 133KB LDS.
// Wave w owns gate rows {2w,2w+1}; lane l owns f4 col-chunks (bank-clean).
// s_in layout (persistent): feat[0,512) | h1[512,1536) | h2[1536,2560).
__global__ __launch_bounds__(512, 1) void lstm_persist(
    const float* __restrict__ Wih1, const float* __restrict__ Whh1,
    const float* __restrict__ Wih2, const float* __restrict__ Whh2,
    const float* __restrict__ Wl,   const float* __restrict__ Wm,
    const float* __restrict__ bih1, const float* __restrict__ bhh1,
    const float* __restrict__ bih2, const float* __restrict__ bhh2,
    const float* __restrict__ blp,  const float* __restrict__ bmp,
    char* __restrict__ wsb, float* __restrict__ out)
{
  extern __shared__ float smem[];
  float* s_in = smem;               // feat | h1 | h2 (persistent regions)
  float* wa   = smem + OFF_WA;      // [16][1024] = WCL rows
  float* wb   = smem + OFF_WB;      // [16][768]  = Whh2 cols 256..1023 (init: WCtmp)
  float* wy   = smem + OFF_WY;      // [2][1024]  = Wl rows wid*2, wid*2+1
  __shared__ float s_part[16];
  __shared__ float s_sums[32];

  u32x4* rh1 = (u32x4*)(wsb + WS_RH1);   // [2][512]
  u32x4* rh2 = (u32x4*)(wsb + WS_RH2);   // [2][512]
  u32x4* ry  = (u32x4*)(wsb + WS_RY);    // [2][256]
  const float* featp = (const float*)(wsb + WS_FEAT);

  const int wid = blockIdx.x, tid = threadIdx.x;
  const int w = tid >> 6, l = tid & 63;
  const int o0 = 2*w, o1 = 2*w + 1;
  const int rA0 = (o0 >> 2)*1024 + wid*4 + (o0 & 3);
  const int rA1 = (o1 >> 2)*1024 + wid*4 + (o1 & 3);

  // ===== init 1: stage this wg's 16 Wih1e rows (16x128) into s_in =====
  for (int idx = tid; idx < 2048; idx += 512){
    int o = idx >> 7, e = idx & 127;
    int r = (o >> 2)*1024 + wid*4 + (o & 3);
    s_in[idx] = Wih1[r*640 + 512 + e];
  }
  __syncthreads();

  // ===== init 2: WCtmp = Wih1e @ Wm  (16x512) -> wb area =====
  {
    float4 a00 = {0,0,0,0}, a01 = a00, a10 = a00, a11 = a00;
    for (int e = 0; e < 128; e++){
      float w0e = s_in[o0*128 + e], w1e = s_in[o1*128 + e];
      float4 m0 = *(const float4*)&Wm[e*512 + l*4];
      float4 m1 = *(const float4*)&Wm[e*512 + l*4 + 256];
      FMA4(a00, w0e, m0); FMA4(a01, w0e, m1);
      FMA4(a10, w1e, m0); FMA4(a11, w1e, m1);
    }
    *(float4*)&wb[o0*512 + l*4]       = a00;
    *(float4*)&wb[o0*512 + l*4 + 256] = a01;
    *(float4*)&wb[o1*512 + l*4]       = a10;
    *(float4*)&wb[o1*512 + l*4 + 256] = a11;
  }
  __syncthreads();

  // ===== init 3: WCL = WCtmp @ Wl (16x1024) -> wa; WC@bl piggyback =====
  {
    float4 c00={0,0,0,0}, c01=c00, c02=c00, c03=c00;
    float4 c10=c00, c11=c00, c12=c00, c13=c00;
    float wl0=0.f, wl1=0.f;
    for (int m = 0; m < 512; m++){
      float t0 = wb[o0*512 + m], t1 = wb[o1*512 + m];
      float blm = blp[m];
      wl0 += t0*blm; wl1 += t1*blm;
      float4 q0 = *(const float4*)&Wl[m*1024 + l*4];
      float4 q1 = *(const float4*)&Wl[m*1024 + l*4 + 256];
      float4 q2 = *(const float4*)&Wl[m*1024 + l*4 + 512];
      float4 q3 = *(const float4*)&Wl[m*1024 + l*4 + 768];
      FMA4(c00,t0,q0); FMA4(c01,t0,q1); FMA4(c02,t0,q2); FMA4(c03,t0,q3);
      FMA4(c10,t1,q0); FMA4(c11,t1,q1); FMA4(c12,t1,q2); FMA4(c13,t1,q3);
    }
    *(float4*)&wa[o0*1024 + l*4      ] = c00;
    *(float4*)&wa[o0*1024 + l*4 + 256] = c01;
    *(float4*)&wa[o0*1024 + l*4 + 512] = c02;
    *(float4*)&wa[o0*1024 + l*4 + 768] = c03;
    *(float4*)&wa[o1*1024 + l*4      ] = c10;
    *(float4*)&wa[o1*1024 + l*4 + 256] = c11;
    *(float4*)&wa[o1*1024 + l*4 + 512] = c12;
    *(float4*)&wa[o1*1024 + l*4 + 768] = c13;
    if (l == 0){ s_sums[w*2+0] = wl0; s_sums[w*2+1] = wl1; }
  }
  __syncthreads();

  // ===== init 4: per-row bias regs (wave 0); rsWC from resident WCtmp =====
  float biasAreg=0.f, biasBreg=0.f, bE2reg=0.f, rsReg=0.f;
  float bl0=0.f, bl1=0.f, c1=0.f, c2=0.f;
  if (w == 0 && l < 16){
    int r = (l >> 2)*1024 + wid*4 + (l & 3);
    biasAreg = bih1[r] + bhh1[r];
    biasBreg = bih2[r] + bhh2[r];
    float acc = s_sums[(l>>1)*2 + (l&1)];     // WC@bl for this row
    for (int e = 0; e < 128; e++) acc += s_in[l*128 + e] * bmp[e];
    bE2reg = acc;
    float rsum = 0.f;
    for (int m = 0; m < 512; m += 4){
      float4 v = *(float4*)&wb[l*512 + m];    // WCtmp row l (still resident)
      rsum += v.x + v.y + v.z + v.w;
    }
    rsReg = rsum;
  }
  if (w == 0 && l == 0){ bl0 = blp[wid*2]; bl1 = blp[wid*2 + 1]; }
  __syncthreads();     // init4's s_in/wb reads done before overwrite below

  // ===== init 5: zero h1/h2 regions; LDS weights wb (Whh2) and wy (Wl) ====
  for (int idx = tid; idx < 2048; idx += 512) s_in[512 + idx] = 0.f;
  for (int o = 0; o < 16; o++){
    int r = (o >> 2)*1024 + wid*4 + (o & 3);
    for (int c = tid; c < 768; c += 512)
      wb[o*768 + c] = Whh2[r*1024 + 256 + c];
  }
  for (int idx = tid; idx < 2048; idx += 512){
    int row = idx >> 10, c = idx & 1023;
    wy[idx] = Wl[(wid*2 + row)*1024 + c];
  }

  // ===== init 6: pinned register weights (88 floats/thread) =====
  float4 wA0[6], wA1[6], wB0[5], wB1[5];
  #pragma unroll
  for (int j = 0; j < 6; j++){
    int c = 256*j + l*4;
    wA0[j] = (c < 512) ? *(const float4*)&Wih1[rA0*640 + c]
                       : *(const float4*)&Whh1[rA0*1024 + c - 512];
    wA1[j] = (c < 512) ? *(const float4*)&Wih1[rA1*640 + c]
                       : *(const float4*)&Whh1[rA1*1024 + c - 512];
  }
  #pragma unroll
  for (int j = 0; j < 5; j++){
    int c = 256*j + l*4;
    wB0[j] = (c < 1024) ? *(const float4*)&Wih2[rA0*1024 + c]
                        : *(const float4*)&Whh2[rA0*1024 + c - 1024];
    wB1[j] = (c < 1024) ? *(const float4*)&Wih2[rA1*1024 + c]
                        : *(const float4*)&Whh2[rA1*1024 + c - 1024];
  }
  #pragma unroll
  for (int j = 0; j < 6; j++){ PIN4(wA0[j]); PIN4(wA1[j]); }
  #pragma unroll
  for (int j = 0; j < 5; j++){ PIN4(wB0[j]); PIN4(wB1[j]); }
  PIN1(biasAreg); PIN1(biasBreg); PIN1(bE2reg); PIN1(rsReg);
  PIN1(bl0); PIN1(bl1);
  __syncthreads();

  // ===== main loop =====
  for (int t = 0; t < T_STEPS; t++){
    const int pprev = (t + 1) & 1;       // parity of step t-1
    const int pcur  = t & 1;             // parity of step t

    // ---- A1: stage feat(t) (h1(t-1) already in s_in[512,1536) from B) ----
    if (tid < 256)
      *(float2*)&s_in[tid*2] = *(const float2*)&featp[(size_t)t*512 + tid*2];
    __syncthreads();

    // ---- A2: partial gates1 (feat+h1 cols, reg weights) -- NO h2 dep ----
    float acc0 = 0.f, acc1 = 0.f;
    #pragma unroll
    for (int j = 0; j < 6; j++){
      float4 xv = *(float4*)&s_in[256*j + l*4];
      acc0 += DOT4(wA0[j], xv); acc1 += DOT4(wA1[j], xv);
    }

    // ---- A3: poll h2(t-1) record (hidden partly under A2's flight) ----
    if (t > 0){
      const u32x4* p2 = rh2 + pprev*512 + tid;
      u32x4 b;
      for(;;){
        b = ld16(p2);
        if (b.z >= (unsigned)t) break;
        __builtin_amdgcn_s_sleep(1);
      }
      *(float2*)&s_in[1536 + 2*tid] =
          make_float2(__uint_as_float(b.x), __uint_as_float(b.y));
    }
    __syncthreads();

    // ---- A4: wave0: y(t-1) full dot + publish; all: WCL dot + pB ----
    if (t > 0 && w == 0){
      float y0 = 0.f, y1 = 0.f;
      #pragma unroll
      for (int i = 0; i < 4; i++){
        float4 xv = *(float4*)&s_in[1536 + 256*i + l*4];
        float4 w0 = *(float4*)&wy[256*i + l*4];
        float4 w1 = *(float4*)&wy[1024 + 256*i + l*4];
        y0 += DOT4(w0, xv); y1 += DOT4(w1, xv);
      }
      #pragma unroll
      for (int mk = 32; mk; mk >>= 1){
        y0 += __shfl_xor(y0, mk); y1 += __shfl_xor(y1, mk);
      }
      if (l == 0){
        y0 += bl0; y1 += bl1;
        *(float2*)&out[(size_t)(t-1)*512 + wid*2] = make_float2(y0, y1);
        u32x4 rec;
        rec.x = __float_as_uint(y0); rec.y = __float_as_uint(y1);
        rec.z = (unsigned)t; rec.w = 0u;
        st16(ry + pcur*256 + wid, rec);
      }
    }
    #pragma unroll
    for (int k = 0; k < 4; k++){
      float4 xv = *(float4*)&s_in[1536 + 256*k + l*4];
      float4 u0 = *(float4*)&wa[o0*1024 + 256*k + l*4];
      float4 u1 = *(float4*)&wa[o1*1024 + 256*k + l*4];
      acc0 += DOT4(u0, xv); acc1 += DOT4(u1, xv);
    }
    #pragma unroll
    for (int mk = 32; mk; mk >>= 1){
      acc0 += __shfl_xor(acc0, mk); acc1 += __shfl_xor(acc1, mk);
    }
    if (l == 0){ s_part[o0] = acc0; s_part[o1] = acc1; }

    // pB: precompute gates2's h2-dependent half (h2 in s_in[1536,2560))
    float pB0, pB1;
    {
      float4 xv = *(float4*)&s_in[1536 + l*4];
      pB0 = DOT4(wB0[4], xv); pB1 = DOT4(wB1[4], xv);
      #pragma unroll
      for (int k = 0; k < 3; k++){
        float4 x2 = *(float4*)&s_in[1536 + 256 + 256*k + l*4];
        float4 u0 = *(float4*)&wb[o0*768 + 256*k + l*4];
        float4 u1 = *(float4*)&wb[o1*768 + 256*k + l*4];
        pB0 += DOT4(u0, x2); pB1 += DOT4(u1, x2);
      }
    }
    __syncthreads();

    // ---- A5: finalize (wave0): batched lse poll, gates, publish rh1 ----
    if (w == 0){
      float lse = 0.f;
      if (t > 0){
        const u32x4* pyr = ry + pcur*256 + 4*l;
        u32x4 r0, r1, r2, r3;
        for(;;){
          ld16x4(pyr, r0, r1, r2, r3);
          if (r0.z >= (unsigned)t && r1.z >= (unsigned)t &&
              r2.z >= (unsigned)t && r3.z >= (unsigned)t) break;
          __builtin_amdgcn_s_sleep(1);
        }
        float v0 = __uint_as_float(r0.x), v1 = __uint_as_float(r0.y);
        float v2 = __uint_as_float(r1.x), v3 = __uint_as_float(r1.y);
        float v4 = __uint_as_float(r2.x), v5 = __uint_as_float(r2.y);
        float v6 = __uint_as_float(r3.x), v7 = __uint_as_float(r3.y);
        float m0 = fmaxf(fmaxf(fmaxf(v0,v1), fmaxf(v2,v3)),
                         fmaxf(fmaxf(v4,v5), fmaxf(v6,v7)));
        #pragma unroll
        for (int mk = 32; mk; mk >>= 1) m0 = fmaxf(m0, __shfl_xor(m0, mk));
        float s = expf(v0-m0)+expf(v1-m0)+expf(v2-m0)+expf(v3-m0)
                + expf(v4-m0)+expf(v5-m0)+expf(v6-m0)+expf(v7-m0);
        #pragma unroll
        for (int mk = 32; mk; mk >>= 1) s += __shfl_xor(s, mk);
        lse = m0 + logf(s);
      }
      float hn = 0.f;
      if (l < 16){
        float sum = s_part[l] + biasAreg;
        if (t > 0) sum += bE2reg - rsReg*lse;
        float gi = __shfl(sum, (l & 3));
        float gf = __shfl(sum, 4 + (l & 3));
        float gg = __shfl(sum, 8 + (l & 3));
        float go = __shfl(sum, 12 + (l & 3));
        if (l < 4){
          float cn = sigm(gf)*c1 + sigm(gi)*tanhf(gg);
          c1 = cn;
          hn = sigm(go)*tanhf(cn);
        }
      }
      float g0 = __shfl(hn, 2*(l & 1));
      float g1 = __shfl(hn, 2*(l & 1) + 1);
      if (l < 2){
        u32x4 rec;
        rec.x = __float_as_uint(g0); rec.y = __float_as_uint(g1);
        rec.z = (unsigned)(t + 1); rec.w = 0u;
        st16(rh1 + pcur*512 + wid*2 + l, rec);
      }
    }

    // ---- B1: poll h1(t) records -> s_in[512,1536) ----
    {
      const u32x4* p1 = rh1 + pcur*512 + tid;
      u32x4 a;
      for(;;){
        a = ld16(p1);
        if (a.z >= (unsigned)(t + 1)) break;
        __builtin_amdgcn_s_sleep(1);
      }
      *(float2*)&s_in[512 + 2*tid] =
          make_float2(__uint_as_float(a.x), __uint_as_float(a.y));
    }
    __syncthreads();

    // ---- B2: gates2 dot: regs j=0..3 on h1 + precomputed pB ----
    float b0 = pB0, b1 = pB1;
    #pragma unroll
    for (int j = 0; j < 4; j++){
      float4 xv = *(float4*)&s_in[512 + 256*j + l*4];
      b0 += DOT4(wB0[j], xv); b1 += DOT4(wB1[j], xv);
    }
    #pragma unroll
    for (int mk = 32; mk; mk >>= 1){
      b0 += __shfl_xor(b0, mk); b1 += __shfl_xor(b1, mk);
    }
    if (l == 0){ s_part[o0] = b0; s_part[o1] = b1; }
    __syncthreads();

    // ---- B3: finalize (wave0), publish rh2 ----
    if (w == 0){
      float hn = 0.f;
      if (l < 16){
        float sum = s_part[l] + biasBreg;
        float gi = __shfl(sum, (l & 3));
        float gf = __shfl(sum, 4 + (l & 3));
        float gg = __shfl(sum, 8 + (l & 3));
        float go = __shfl(sum, 12 + (l & 3));
        if (l < 4){
          float cn = sigm(gf)*c2 + sigm(gi)*tanhf(gg);
          c2 = cn;
          hn = sigm(go)*tanhf(cn);
        }
      }
      float g0 = __shfl(hn, 2*(l & 1));
      float g1 = __shfl(hn, 2*(l & 1) + 1);
      if (l < 2){
        u32x4 rec;
        rec.x = __float_as_uint(g0); rec.y = __float_as_uint(g1);
        rec.z = (unsigned)(t + 1); rec.w = 0u;
        st16(rh2 + pcur*512 + wid*2 + l, rec);
      }
    }
  }

  // ===== tail: y(T-1) from rh2[(T-1)&1] records =====
  {
    const u32x4* p2 = rh2 + ((T_STEPS - 1) & 1)*512 + tid;
    u32x4 b;
    for(;;){
      b = ld16(p2);
      if (b.z >= (unsigned)T_STEPS) break;
      __builtin_amdgcn_s_sleep(1);
    }
    *(float2*)&s_in[1536 + 2*tid] =
        make_float2(__uint_as_float(b.x), __uint_as_float(b.y));
  }
  __syncthreads();
  if (w == 0){
    float y0 = 0.f, y1 = 0.f;
    #pragma unroll
    for (int i = 0; i < 4; i++){
      float4 xv = *(float4*)&s_in[1536 + 256*i + l*4];
      float4 w0 = *(float4*)&wy[256*i + l*4];
      float4 w1 = *(float4*)&wy[1024 + 256*i + l*4];
      y0 += DOT4(w0, xv); y1 += DOT4(w1, xv);
    }
    #pragma unroll
    for (int mk = 32; mk; mk >>= 1){
      y0 += __shfl_xor(y0, mk); y1 += __shfl_xor(y1, mk);
    }
    if (l == 0)
      *(float2*)&out[(size_t)(T_STEPS-1)*512 + wid*2] =
          make_float2(y0 + bl0, y1 + bl1);
  }
}

// ---------------------------------------------------------------------------
extern "C" void kernel_launch(void* const* d_in, const int* in_sizes, int n_in,
                              void* d_out, int out_size, void* d_ws, size_t ws_size,
                              hipStream_t stream)
{
  const float* x    = (const float*)d_in[0];
  const float* Ws   = (const float*)d_in[1];
  const float* bs   = (const float*)d_in[2];
  const float* Wih1 = (const float*)d_in[3];
  const float* Whh1 = (const float*)d_in[4];
  const float* bih1 = (const float*)d_in[5];
  const float* bhh1 = (const float*)d_in[6];
  const float* Wih2 = (const float*)d_in[7];
  const float* Whh2 = (const float*)d_in[8];
  const float* bih2 = (const float*)d_in[9];
  const float* bhh2 = (const float*)d_in[10];
  const float* Wl   = (const float*)d_in[11];
  const float* bl   = (const float*)d_in[12];
  const float* Wm   = (const float*)d_in[13];
  const float* bm   = (const float*)d_in[14];
  char* wsb  = (char*)d_ws;
  float* out = (float*)d_out;

  // zero records (seq=0 < any need) -- fresh each call / graph replay
  hipMemsetAsync(wsb, 0, WS_ZERO_BYTES, stream);

  feat_kernel<<<256, 512, 0, stream>>>(x, Ws, bs, (float*)(wsb + WS_FEAT));
  lstm_persist<<<NWG, 512, SMEM_BYTES, stream>>>(
      Wih1, Whh1, Wih2, Whh2, Wl, Wm,
      bih1, bhh1, bih2, bhh2, bl, bm, wsb, out);
  ls_kernel<<<T_STEPS, 64, 0, stream>>>(out);
}